// Round 16
// baseline (409.887 us; speedup 1.0000x reference)
//
#include <hip/hip_runtime.h>
#include <hip/hip_bf16.h>
#include <math.h>

// Problem constants
#define Bn 4
#define Ln 1024
#define Vn 64
#define Dn 256
#define Hn 4
#define DKn 64
#define NLn 4
#define Mn 20
#define FFn 1024
#define NTOK (Bn * Ln)   // 4096
#define QKVW 768         // fused q|k|v width
#define LOG2E 1.4426950408889634f
#define PELEMS (Bn * Hn * Ln * Ln)   // 16777216 elements per layer P

typedef __attribute__((ext_vector_type(8))) short bf16x8;
typedef __attribute__((ext_vector_type(4))) float f32x4;

__device__ __forceinline__ ushort f2b(float f) {   // fp32 -> bf16 RNE
    uint u = __float_as_uint(f);
    u += 0x7fff + ((u >> 16) & 1);
    return (ushort)(u >> 16);
}
__device__ __forceinline__ float b2f(ushort u) {   // exact
    return __uint_as_float(((uint)u) << 16);
}

// ---------------------------------------------------------------------------
__global__ __launch_bounds__(256) void embed_k(const float* __restrict__ X,
                                               const float* __restrict__ E,
                                               ushort* __restrict__ Hb) {
    __shared__ float xs[Vn];
    int n = blockIdx.x, d = threadIdx.x;
    if (threadIdx.x < Vn) xs[threadIdx.x] = X[n * Vn + threadIdx.x];
    __syncthreads();
    float s = 0.f;
#pragma unroll
    for (int v = 0; v < Vn; ++v) s += xs[v] * E[v * Dn + d];
    Hb[(size_t)n * Dn + d] = f2b(s);
}

// ---------------------------------------------------------------------------
__global__ __launch_bounds__(256) void relbias_k(const float* __restrict__ rk,
                                                 const float* __restrict__ rb,
                                                 float* __restrict__ bkT,
                                                 float* __restrict__ bbT) {
    int tid = blockIdx.x * 256 + threadIdx.x;   // < NL*H*1024
    int dist = tid & 1023;
    int hh = (tid >> 10) & 3;
    int l = tid >> 12;
    float dd = (float)dist;
    if (dist > Mn) dd = (float)Mn + log2f((float)(dist - Mn));
    if (dd > 2.0f * Mn) dd = 2.0f * Mn;
    int idx = (int)dd;
    bkT[tid] = rk[(l * (2 * Mn + 1) + idx) * Hn + hh] * 0.125f * LOG2E;
    bbT[tid] = rb[(l * (2 * Mn + 1) + idx) * Hn + hh] * LOG2E;
}

// ---------------------------------------------------------------------------
__global__ __launch_bounds__(256) void prep_bias(const float* __restrict__ bq,
                                                 const float* __restrict__ bk,
                                                 const float* __restrict__ bv,
                                                 float* __restrict__ bqkv) {
    int idx = blockIdx.x * 256 + threadIdx.x;   // < NL*768
    int l = idx / QKVW, r = idx - l * QKVW;
    float v;
    if (r < 256)      v = bq[l * 256 + r];
    else if (r < 512) v = bk[l * 256 + r - 256];
    else              v = bv[l * 256 + r - 512];
    bqkv[idx] = v;
}

// ---------------------------------------------------------------------------
__global__ __launch_bounds__(256) void transpose_cvt(
    const float* __restrict__ src, ushort* __restrict__ dst,
    int R, int C, int srcLS, int dstLS) {
    __shared__ float s[32][33];
    src += (size_t)blockIdx.z * srcLS;
    dst += (size_t)blockIdx.z * dstLS;
    int r0 = blockIdx.y * 32, c0 = blockIdx.x * 32;
    int tx = threadIdx.x & 31, ty = threadIdx.x >> 5;
#pragma unroll
    for (int ii = 0; ii < 4; ++ii)
        s[ty + 8 * ii][tx] = src[(size_t)(r0 + ty + 8 * ii) * C + c0 + tx];
    __syncthreads();
#pragma unroll
    for (int ii = 0; ii < 4; ++ii)
        dst[(size_t)(c0 + ty + 8 * ii) * R + r0 + tx] = f2b(s[tx][ty + 8 * ii]);
}

// ---------------------------------------------------------------------------
// Legacy 64x64 bf16 MFMA GEMM (Wo + fallback), BK=64. Proven structure.
#define GST 72
#define GEMM_KK_MFMA(KK)                                                      \
    {                                                                         \
        bf16x8 a0 = *(const bf16x8*)&As[(wm * 32 + l15) * GST + (KK)*32 + lg * 8];      \
        bf16x8 a1 = *(const bf16x8*)&As[(wm * 32 + 16 + l15) * GST + (KK)*32 + lg * 8]; \
        bf16x8 b0 = *(const bf16x8*)&Bs[(wn * 32 + l15) * GST + (KK)*32 + lg * 8];      \
        bf16x8 b1 = *(const bf16x8*)&Bs[(wn * 32 + 16 + l15) * GST + (KK)*32 + lg * 8]; \
        acc[0][0] = __builtin_amdgcn_mfma_f32_16x16x32_bf16(a0, b0, acc[0][0], 0, 0, 0); \
        acc[0][1] = __builtin_amdgcn_mfma_f32_16x16x32_bf16(a0, b1, acc[0][1], 0, 0, 0); \
        acc[1][0] = __builtin_amdgcn_mfma_f32_16x16x32_bf16(a1, b0, acc[1][0], 0, 0, 0); \
        acc[1][1] = __builtin_amdgcn_mfma_f32_16x16x32_bf16(a1, b1, acc[1][1], 0, 0, 0); \
    }

template <int LNA>
__global__ __launch_bounds__(256) void gemm_mfma(
    const ushort* __restrict__ A, const ushort* __restrict__ Bt,
    const float* __restrict__ bias, ushort* __restrict__ C,
    int M, int N, int K, int act,
    const float* __restrict__ lng, const float* __restrict__ lnb,
    ushort* __restrict__ Vt_out) {
    __shared__ __align__(16) ushort As[64 * GST];
    __shared__ __align__(16) ushort Bs[64 * GST];
    __shared__ float gl[256];
    __shared__ float bl[256];
    int t = threadIdx.x;
    int lane = t & 63, w = t >> 6;
    int wm = w >> 1, wn = w & 1;
    int l15 = lane & 15, lg = lane >> 4;
    int mBase = blockIdx.y * 64, nBase = blockIdx.x * 64;
    int lrow = t >> 2, lkc = (t & 3) * 16;
    const ushort* Ap = A + (size_t)(mBase + lrow) * K + lkc;
    const ushort* Bp = Bt + (size_t)(nBase + lrow) * K + lkc;
    f32x4 acc[2][2] = {};

    if constexpr (LNA) {
        uint4 areg[8];
        float s = 0.f;
#pragma unroll
        for (int kc = 0; kc < 4; ++kc)
#pragma unroll
            for (int h = 0; h < 2; ++h) {
                areg[kc * 2 + h] = *(const uint4*)(Ap + kc * 64 + h * 8);
                const ushort* e = (const ushort*)&areg[kc * 2 + h];
#pragma unroll
                for (int q = 0; q < 8; ++q) s += b2f(e[q]);
            }
        s += __shfl_xor(s, 1, 64);
        s += __shfl_xor(s, 2, 64);
        float mu = s * (1.0f / 256.0f);
        float vv = 0.f;
#pragma unroll
        for (int kc = 0; kc < 8; ++kc) {
            const ushort* e = (const ushort*)&areg[kc];
#pragma unroll
            for (int q = 0; q < 8; ++q) {
                float d = b2f(e[q]) - mu;
                vv += d * d;
            }
        }
        vv += __shfl_xor(vv, 1, 64);
        vv += __shfl_xor(vv, 2, 64);
        float rs = rsqrtf(vv * (1.0f / 256.0f) + 1e-5f);
        gl[t] = lng[t];
        bl[t] = lnb[t];
        __syncthreads();
#pragma unroll
        for (int kc = 0; kc < 4; ++kc) {
            uint4 bv0 = *(const uint4*)(Bp + kc * 64);
            uint4 bv1 = *(const uint4*)(Bp + kc * 64 + 8);
            __syncthreads();
#pragma unroll
            for (int h = 0; h < 2; ++h) {
                const ushort* e = (const ushort*)&areg[kc * 2 + h];
                ushort outv[8];
#pragma unroll
                for (int q = 0; q < 8; ++q) {
                    int col = kc * 64 + lkc + h * 8 + q;
                    outv[q] = f2b((b2f(e[q]) - mu) * rs * gl[col] + bl[col]);
                }
                *(uint4*)&As[lrow * GST + lkc + h * 8] = *(const uint4*)outv;
            }
            *(uint4*)&Bs[lrow * GST + lkc] = bv0;
            *(uint4*)&Bs[lrow * GST + lkc + 8] = bv1;
            __syncthreads();
            GEMM_KK_MFMA(0)
            GEMM_KK_MFMA(1)
        }
    } else {
        for (int k0 = 0; k0 < K; k0 += 64) {
            uint4 av0 = *(const uint4*)(Ap + k0);
            uint4 av1 = *(const uint4*)(Ap + k0 + 8);
            uint4 bv0 = *(const uint4*)(Bp + k0);
            uint4 bv1 = *(const uint4*)(Bp + k0 + 8);
            __syncthreads();
            *(uint4*)&As[lrow * GST + lkc] = av0;
            *(uint4*)&As[lrow * GST + lkc + 8] = av1;
            *(uint4*)&Bs[lrow * GST + lkc] = bv0;
            *(uint4*)&Bs[lrow * GST + lkc + 8] = bv1;
            __syncthreads();
            GEMM_KK_MFMA(0)
            GEMM_KK_MFMA(1)
        }
    }
    if (Vt_out != nullptr && nBase >= 512) {
#pragma unroll
        for (int ni = 0; ni < 2; ++ni) {
            int col = nBase + wn * 32 + ni * 16 + l15;
            float bc = bias[col];
            int d = col - 512;
#pragma unroll
            for (int mi = 0; mi < 2; ++mi) {
                int rb = mBase + wm * 32 + mi * 16 + lg * 4;
                int bb_ = rb >> 10, i_ = rb & 1023;
                size_t vb = ((size_t)(bb_ * 4 + (d >> 6)) * 64 + (d & 63)) * Ln + i_;
                ushort o4[4];
#pragma unroll
                for (int j = 0; j < 4; ++j) o4[j] = f2b(acc[mi][ni][j] + bc);
                *(ushort4*)&Vt_out[vb] = *(const ushort4*)o4;
            }
        }
        return;
    }
#pragma unroll
    for (int ni = 0; ni < 2; ++ni) {
        int col = nBase + wn * 32 + ni * 16 + l15;
        float bc = bias[col];
#pragma unroll
        for (int mi = 0; mi < 2; ++mi) {
            int rb = mBase + wm * 32 + mi * 16 + lg * 4;
#pragma unroll
            for (int j = 0; j < 4; ++j) {
                float v = acc[mi][ni][j] + bc;
                if (act) v = v * 0.5f * (1.0f + erff(v * 0.7071067811865475f));
                C[(size_t)(rb + j) * N + col] = f2b(v);
            }
        }
    }
}

// ---------------------------------------------------------------------------
// 128x128 bf16 MFMA GEMM v2 — 8 waves, wave = 64x32 sub-tile, K chunk = 256.
#define G2ST 72
template <int LNA, int SPLITK>
__global__ __launch_bounds__(512) void gemm128(
    const ushort* __restrict__ A, const ushort* __restrict__ Bt,
    const float* __restrict__ bias, ushort* __restrict__ C,
    float* __restrict__ Cpart,
    int M, int N, int K, int act,
    const float* __restrict__ lng, const float* __restrict__ lnb,
    ushort* __restrict__ Vt_out) {
    __shared__ __align__(16) ushort As[128 * G2ST];
    __shared__ __align__(16) ushort Bs[128 * G2ST];
    __shared__ float gl[256];
    __shared__ float bl[256];
    int t = threadIdx.x;
    int lane = t & 63, w = t >> 6;
    int wm = w >> 2, wn = w & 3;
    int l15 = lane & 15, lg = lane >> 4;
    int mBase = blockIdx.y * 128, nBase = blockIdx.x * 128;
    int srow = t >> 2, skof = (t & 3) * 16;
    int kbeg = (SPLITK > 1) ? blockIdx.z * 256 : 0;
    const ushort* Ap = A + (size_t)(mBase + srow) * K + kbeg + skof;
    const ushort* Bp = Bt + (size_t)(nBase + srow) * K + kbeg + skof;
    f32x4 acc[4][2] = {};

    float mu = 0.f, rs = 0.f;
    uint4 areg[8];
    if constexpr (LNA) {
        float s = 0.f;
#pragma unroll
        for (int kc = 0; kc < 4; ++kc)
#pragma unroll
            for (int h = 0; h < 2; ++h) {
                areg[kc * 2 + h] = *(const uint4*)(Ap + kc * 64 + h * 8);
                const ushort* e = (const ushort*)&areg[kc * 2 + h];
#pragma unroll
                for (int z = 0; z < 8; ++z) s += b2f(e[z]);
            }
        s += __shfl_xor(s, 1, 64);
        s += __shfl_xor(s, 2, 64);
        mu = s * (1.0f / 256.0f);
        float vv = 0.f;
#pragma unroll
        for (int q = 0; q < 8; ++q) {
            const ushort* e = (const ushort*)&areg[q];
#pragma unroll
            for (int z = 0; z < 8; ++z) {
                float d = b2f(e[z]) - mu;
                vv += d * d;
            }
        }
        vv += __shfl_xor(vv, 1, 64);
        vv += __shfl_xor(vv, 2, 64);
        rs = rsqrtf(vv * (1.0f / 256.0f) + 1e-5f);
        if (t < 256) {
            gl[t] = lng[t];
            bl[t] = lnb[t];
        }
    }

#pragma unroll
    for (int kc = 0; kc < 4; ++kc) {
        uint4 av0, av1, bv0, bv1;
        if constexpr (!LNA) {
            av0 = *(const uint4*)(Ap + kc * 64);
            av1 = *(const uint4*)(Ap + kc * 64 + 8);
        }
        bv0 = *(const uint4*)(Bp + kc * 64);
        bv1 = *(const uint4*)(Bp + kc * 64 + 8);
        __syncthreads();
        if constexpr (LNA) {
#pragma unroll
            for (int h = 0; h < 2; ++h) {
                const ushort* e = (const ushort*)&areg[kc * 2 + h];
                ushort outv[8];
#pragma unroll
                for (int z = 0; z < 8; ++z) {
                    int col = kc * 64 + skof + h * 8 + z;
                    outv[z] = f2b((b2f(e[z]) - mu) * rs * gl[col] + bl[col]);
                }
                *(uint4*)&As[srow * G2ST + skof + h * 8] = *(const uint4*)outv;
            }
        } else {
            *(uint4*)&As[srow * G2ST + skof] = av0;
            *(uint4*)&As[srow * G2ST + skof + 8] = av1;
        }
        *(uint4*)&Bs[srow * G2ST + skof] = bv0;
        *(uint4*)&Bs[srow * G2ST + skof + 8] = bv1;
        __syncthreads();
#pragma unroll
        for (int kk = 0; kk < 2; ++kk) {
            bf16x8 af[4], bfr[2];
#pragma unroll
            for (int mi = 0; mi < 4; ++mi)
                af[mi] = *(const bf16x8*)&As[(wm * 64 + mi * 16 + l15) * G2ST + kk * 32 + lg * 8];
#pragma unroll
            for (int ni = 0; ni < 2; ++ni)
                bfr[ni] = *(const bf16x8*)&Bs[(wn * 32 + ni * 16 + l15) * G2ST + kk * 32 + lg * 8];
#pragma unroll
            for (int mi = 0; mi < 4; ++mi)
#pragma unroll
                for (int ni = 0; ni < 2; ++ni)
                    acc[mi][ni] = __builtin_amdgcn_mfma_f32_16x16x32_bf16(
                        af[mi], bfr[ni], acc[mi][ni], 0, 0, 0);
        }
    }

    if (Vt_out != nullptr && nBase >= 512) {
#pragma unroll
        for (int ni = 0; ni < 2; ++ni) {
            int col = nBase + wn * 32 + ni * 16 + l15;
            float bc = bias[col];
            int d = col - 512;
#pragma unroll
            for (int mi = 0; mi < 4; ++mi) {
                int rb = mBase + wm * 64 + mi * 16 + lg * 4;
                int bb_ = rb >> 10, i_ = rb & 1023;
                size_t vb = ((size_t)(bb_ * 4 + (d >> 6)) * 64 + (d & 63)) * Ln + i_;
                ushort o4[4];
#pragma unroll
                for (int j = 0; j < 4; ++j) o4[j] = f2b(acc[mi][ni][j] + bc);
                *(ushort4*)&Vt_out[vb] = *(const ushort4*)o4;
            }
        }
        return;
    }
    if constexpr (SPLITK > 1) {
#pragma unroll
        for (int ni = 0; ni < 2; ++ni) {
            int col = nBase + wn * 32 + ni * 16 + l15;
#pragma unroll
            for (int mi = 0; mi < 4; ++mi) {
                int rb = mBase + wm * 64 + mi * 16 + lg * 4;
#pragma unroll
                for (int j = 0; j < 4; ++j)
                    Cpart[((size_t)blockIdx.z * M + rb + j) * N + col] = acc[mi][ni][j];
            }
        }
        return;
    }
#pragma unroll
    for (int ni = 0; ni < 2; ++ni) {
        int col = nBase + wn * 32 + ni * 16 + l15;
        float bc = bias[col];
#pragma unroll
        for (int mi = 0; mi < 4; ++mi) {
            int rb = mBase + wm * 64 + mi * 16 + lg * 4;
#pragma unroll
            for (int j = 0; j < 4; ++j) {
                float v = acc[mi][ni][j] + bc;
                if (act) v = v * 0.5f * (1.0f + erff(v * 0.7071067811865475f));
                C[(size_t)(rb + j) * N + col] = f2b(v);
            }
        }
    }
}

// ---------------------------------------------------------------------------
// FF2 split-K combine: C = bf16(bias + sum_z part[z]); N == 256.
__global__ __launch_bounds__(256) void combine_k(const float* __restrict__ part,
                                                 const float* __restrict__ bias,
                                                 ushort* __restrict__ C) {
    size_t e = ((size_t)blockIdx.x * 256 + threadIdx.x) * 4;   // < 4096*256
    const size_t MN = (size_t)NTOK * Dn;
    float4 s = *(const float4*)&bias[(int)(e & 255)];
#pragma unroll
    for (int z = 0; z < 4; ++z) {
        float4 p = *(const float4*)&part[z * MN + e];
        s.x += p.x; s.y += p.y; s.z += p.z; s.w += p.w;
    }
    ushort4 o;
    o.x = f2b(s.x); o.y = f2b(s.y); o.z = f2b(s.z); o.w = f2b(s.w);
    *(ushort4*)&C[e] = o;
}

// ---------------------------------------------------------------------------
// MFMA flash attention, 16 waves (1024 thr): wave (wc,wn) owns 4 chunks x
// 16-col slice -> per-wave serial chain halved again vs 8-wave. LDS ~50KB ->
// 2 blocks/CU = 32 waves (max). Pw (16x2560) aliased by 8x4096 Opart regions.
// MODE 0: f32 RMW avg. MODE 1: P bf16 tile-linear. MODE 2: final avg f32.
#define PWST 40
#define NW 16
template <int MODE>
__global__ __launch_bounds__(1024, 8) void attn_fused(
    const ushort* __restrict__ qkv, const ushort* __restrict__ Vt,
    const float* __restrict__ bkTab, const float* __restrict__ bbTab,
    ushort* __restrict__ ctx, float* __restrict__ avg,
    ushort* __restrict__ Pout, int first) {
    __shared__ float bk_l[Ln];
    __shared__ float bb_l[Ln];
    __shared__ __align__(16) char uni[NW * 2560];   // Pw | 8x4096 Opart
    __shared__ float mm[NW][16];
    __shared__ float ll[NW][16];

    int t = threadIdx.x;
    int lane = t & 63, w = t >> 6;        // w in [0,16)
    int wn = w & 3, wc = w >> 2;          // col slice, chunk quarter
    int l15 = lane & 15, lg = lane >> 4;

    ushort* pwh = (ushort*)&uni[w * 2560];
    ushort* pwl = (ushort*)&uni[w * 2560 + 1280];

    int bid = blockIdx.x;
    int xcd = bid & 7, sub = bid >> 3;    // sub in [0,128)
    int bh = xcd * 2 + (sub >> 6);
    int q = sub & 63;
    int b = bh >> 2, hh = bh & 3;
    int i0 = q * 16;

    bk_l[t] = bkTab[hh * Ln + t];
    bb_l[t] = bbTab[hh * Ln + t];
    __syncthreads();

    // Q fragment (A-operand): row = i0 + l15, k = lg*8 (+32)
    bf16x8 qa0, qa1;
    {
        const ushort* qp = qkv + (size_t)(b * Ln + i0 + l15) * QKVW + hh * DKn;
        qa0 = *(const bf16x8*)(qp + lg * 8);
        qa1 = *(const bf16x8*)(qp + 32 + lg * 8);
    }

    const ushort* kbase = qkv + (size_t)(b * Ln) * QKVW + Dn + hh * DKn;

    // ---- QK pass over this wave's 4 chunks (barrier-free) -------------------
    f32x4 sv[4];
    float m[4] = {-1e30f, -1e30f, -1e30f, -1e30f};
#pragma unroll
    for (int cl = 0; cl < 4; ++cl) {
        int c = wc * 4 + cl;
        const ushort* kp = kbase + (size_t)(c * 64 + wn * 16 + l15) * QKVW;
        bf16x8 k0 = *(const bf16x8*)(kp + lg * 8);
        bf16x8 k1 = *(const bf16x8*)(kp + 32 + lg * 8);
        f32x4 acc = {};
        acc = __builtin_amdgcn_mfma_f32_16x16x32_bf16(qa0, k0, acc, 0, 0, 0);
        acc = __builtin_amdgcn_mfma_f32_16x16x32_bf16(qa1, k1, acc, 0, 0, 0);
        int j = c * 64 + wn * 16 + l15;
#pragma unroll
        for (int r = 0; r < 4; ++r) {
            int i = i0 + lg * 4 + r;
            int dist = (i > j) ? (i - j) : (j - i);
            float s = acc[r] * bk_l[dist] + bb_l[dist];
            sv[cl][r] = s;
            m[r] = fmaxf(m[r], s);
        }
    }
    // merge max over the 16 l15-lanes
#pragma unroll
    for (int mask = 1; mask < 16; mask <<= 1)
#pragma unroll
        for (int r = 0; r < 4; ++r) m[r] = fmaxf(m[r], __shfl_xor(m[r], mask, 64));
    // merge max across the 16 waves
    if (l15 == 0)
#pragma unroll
        for (int r = 0; r < 4; ++r) mm[w][lg * 4 + r] = m[r];
    __syncthreads();
#pragma unroll
    for (int r = 0; r < 4; ++r) {
        int row = lg * 4 + r;
        float mx = mm[0][row];
#pragma unroll
        for (int wv = 1; wv < NW; ++wv) mx = fmaxf(mx, mm[wv][row]);
        m[r] = mx;
    }
    // p_unnorm = exp2(s - m); row sums
    float lsum[4] = {0.f, 0.f, 0.f, 0.f};
#pragma unroll
    for (int cl = 0; cl < 4; ++cl)
#pragma unroll
        for (int r = 0; r < 4; ++r) {
            float p = exp2f(sv[cl][r] - m[r]);
            sv[cl][r] = p;
            lsum[r] += p;
        }
#pragma unroll
    for (int mask = 1; mask < 16; mask <<= 1)
#pragma unroll
        for (int r = 0; r < 4; ++r) lsum[r] += __shfl_xor(lsum[r], mask, 64);
    if (l15 == 0)
#pragma unroll
        for (int r = 0; r < 4; ++r) ll[w][lg * 4 + r] = lsum[r];
    __syncthreads();
    float invl[4];
#pragma unroll
    for (int r = 0; r < 4; ++r) {
        int row = lg * 4 + r;
        float sm = ll[0][row];
#pragma unroll
        for (int wv = 1; wv < NW; ++wv) sm += ll[wv][row];
        invl[r] = 1.0f / sm;
    }

    // ---- PV partial-O + P/avg output: ZERO barriers --------------------------
    const ushort* vbase = Vt + (size_t)bh * DKn * Ln;       // [64 d][Ln k]
    float* avgrow = avg + ((size_t)bh * Ln + i0) * Ln;      // MODE 0
    int iw = lane >> 2, jq = lane & 3;                      // P tile map
    f32x4 acco[4] = {};
#pragma unroll
    for (int p = 0; p < 2; ++p) {
        const int c0 = wc * 4 + 2 * p, c1 = c0 + 1;
        float aold[2][4];
        if (MODE == 0 && !first) {
#pragma unroll
            for (int cc = 0; cc < 2; ++cc)
#pragma unroll
                for (int r = 0; r < 4; ++r)
                    aold[cc][r] = avgrow[(size_t)(lg * 4 + r) * Ln +
                                         (c0 + cc) * 64 + wn * 16 + l15];
        }
        // stage P (hi/lo) into wave-private LDS
#pragma unroll
        for (int cc = 0; cc < 2; ++cc)
#pragma unroll
            for (int r = 0; r < 4; ++r) {
                float pv = sv[2 * p + cc][r] * invl[r];
                sv[2 * p + cc][r] = pv;
                ushort ph = f2b(pv);
                int off = (lg * 4 + r) * PWST + cc * 16 + l15;
                pwh[off] = ph;
                pwl[off] = f2b(pv - b2f(ph));
            }
        // V A-fragments
        int kcol = (lg < 2 ? c0 : c1) * 64 + wn * 16 + (lg & 1) * 8;
        bf16x8 va0 = *(const bf16x8*)(vbase + (size_t)(0 * 16 + l15) * Ln + kcol);
        bf16x8 va1 = *(const bf16x8*)(vbase + (size_t)(1 * 16 + l15) * Ln + kcol);
        bf16x8 va2 = *(const bf16x8*)(vbase + (size_t)(2 * 16 + l15) * Ln + kcol);
        bf16x8 va3 = *(const bf16x8*)(vbase + (size_t)(3 * 16 + l15) * Ln + kcol);
        // B fragments from own LDS (same-wave RAW: compiler lgkmcnt)
        bf16x8 pbh = *(const bf16x8*)&pwh[l15 * PWST + lg * 8];
        bf16x8 pbl = *(const bf16x8*)&pwl[l15 * PWST + lg * 8];
        acco[0] = __builtin_amdgcn_mfma_f32_16x16x32_bf16(va0, pbh, acco[0], 0, 0, 0);
        acco[1] = __builtin_amdgcn_mfma_f32_16x16x32_bf16(va1, pbh, acco[1], 0, 0, 0);
        acco[2] = __builtin_amdgcn_mfma_f32_16x16x32_bf16(va2, pbh, acco[2], 0, 0, 0);
        acco[3] = __builtin_amdgcn_mfma_f32_16x16x32_bf16(va3, pbh, acco[3], 0, 0, 0);
        acco[0] = __builtin_amdgcn_mfma_f32_16x16x32_bf16(va0, pbl, acco[0], 0, 0, 0);
        acco[1] = __builtin_amdgcn_mfma_f32_16x16x32_bf16(va1, pbl, acco[1], 0, 0, 0);
        acco[2] = __builtin_amdgcn_mfma_f32_16x16x32_bf16(va2, pbl, acco[2], 0, 0, 0);
        acco[3] = __builtin_amdgcn_mfma_f32_16x16x32_bf16(va3, pbl, acco[3], 0, 0, 0);
        if (MODE == 0) {
#pragma unroll
            for (int cc = 0; cc < 2; ++cc)
#pragma unroll
                for (int r = 0; r < 4; ++r) {
                    float v = 0.25f * sv[2 * p + cc][r];
                    if (!first) v += aold[cc][r];
                    avgrow[(size_t)(lg * 4 + r) * Ln + (c0 + cc) * 64 + wn * 16 + l15] = v;
                }
        } else if (MODE == 1) {
            // tile-linear P store: 512B contiguous per wave per cc
            size_t tb = ((((size_t)bid * NW + w) * 2 + p) * 2) * 256 + (size_t)lane * 4;
            ushort4 ph0 = *(const ushort4*)&pwh[iw * PWST + 0 * 16 + jq * 4];
            ushort4 ph1 = *(const ushort4*)&pwh[iw * PWST + 1 * 16 + jq * 4];
            *(ushort4*)&Pout[tb] = ph0;
            *(ushort4*)&Pout[tb + 256] = ph1;
        } else {
            // MODE 2: read P0..P2 tile-linear, add own P, write avg f32
#pragma unroll
            for (int cc = 0; cc < 2; ++cc) {
                int c = c0 + cc;
                size_t tb = ((((size_t)bid * NW + w) * 2 + p) * 2 + cc) * 256 +
                            (size_t)lane * 4;
                ushort4 p0 = *(const ushort4*)&Pout[tb];
                ushort4 p1 = *(const ushort4*)&Pout[(size_t)PELEMS + tb];
                ushort4 p2 = *(const ushort4*)&Pout[(size_t)2 * PELEMS + tb];
                ushort4 p3 = *(const ushort4*)&pwh[iw * PWST + cc * 16 + jq * 4];
                const ushort* q0 = (const ushort*)&p0;
                const ushort* q1 = (const ushort*)&p1;
                const ushort* q2 = (const ushort*)&p2;
                const ushort* q3 = (const ushort*)&p3;
                size_t base = ((size_t)(bh * Ln) + i0 + iw) * Ln +
                              c * 64 + wn * 16 + jq * 4;
                float4 o;
                float* op_ = (float*)&o;
#pragma unroll
                for (int k = 0; k < 4; ++k)
                    op_[k] = 0.25f * (b2f(q0[k]) + b2f(q1[k]) + b2f(q2[k]) + b2f(q3[k]));
                *(float4*)&avg[base] = o;
            }
        }
    }

    // ---- reduce partial O across 16 waves (Opart aliases Pw) -----------------
    // region r = wn*2 + (wc&1); wc>=2 store, then wc<2 add, then sum 8 regions.
    __syncthreads();   // all PV done; Pw region dead
    {
        float* op = (float*)&uni[(wn * 2 + (wc & 1)) * 4096];
        if (wc >= 2) {
#pragma unroll
            for (int dg = 0; dg < 4; ++dg)
#pragma unroll
                for (int r = 0; r < 4; ++r)
                    op[(dg * 16 + lg * 4 + r) * 16 + l15] = acco[dg][r];
        }
    }
    __syncthreads();
    {
        float* op = (float*)&uni[(wn * 2 + (wc & 1)) * 4096];
        if (wc < 2) {
#pragma unroll
            for (int dg = 0; dg < 4; ++dg)
#pragma unroll
                for (int r = 0; r < 4; ++r)
                    op[(dg * 16 + lg * 4 + r) * 16 + l15] += acco[dg][r];
        }
    }
    __syncthreads();
    {
        int idx = t;          // idx = d*16 + i, 1024 elements
        float v = 0.f;
#pragma unroll
        for (int rg = 0; rg < 8; ++rg)
            v += ((const float*)&uni[rg * 4096])[idx];
        int dd = idx >> 4, ii = idx & 15;
        ctx[(size_t)(b * Ln + i0 + ii) * Dn + hh * DKn + dd] = f2b(v);
    }
}

// ---------------------------------------------------------------------------
__global__ __launch_bounds__(256) void layernorm_k(const ushort* __restrict__ X,
                                                   const float* __restrict__ g,
                                                   const float* __restrict__ bta,
                                                   ushort* __restrict__ Y) {
    int w = threadIdx.x >> 6, lane = threadIdx.x & 63;
    int row = blockIdx.x * 4 + w;
    const ushort* xr = X + (size_t)row * Dn;
    float x[4];
#pragma unroll
    for (int ii = 0; ii < 4; ++ii) x[ii] = b2f(xr[lane + 64 * ii]);
    float s = x[0] + x[1] + x[2] + x[3];
#pragma unroll
    for (int m = 1; m < 64; m <<= 1) s += __shfl_xor(s, m, 64);
    float mu = s * (1.0f / 256.0f);
    float vs = 0.f;
#pragma unroll
    for (int ii = 0; ii < 4; ++ii) {
        float d = x[ii] - mu;
        vs += d * d;
    }
#pragma unroll
    for (int m = 1; m < 64; m <<= 1) vs += __shfl_xor(vs, m, 64);
    float rs = rsqrtf(vs * (1.0f / 256.0f) + 1e-5f);
#pragma unroll
    for (int ii = 0; ii < 4; ++ii) {
        int d = lane + 64 * ii;
        Y[(size_t)row * Dn + d] = f2b((x[ii] - mu) * rs * g[d] + bta[d]);
    }
}

// ---------------------------------------------------------------------------
__global__ __launch_bounds__(256) void mean_part_k(const ushort* __restrict__ Hb,
                                                   float* __restrict__ part) {
    int blk = blockIdx.x;
    int b = blk >> 4, g = blk & 15;
    int d = threadIdx.x;
    float s = 0.f;
#pragma unroll
    for (int r = 0; r < 64; ++r)
        s += b2f(Hb[(size_t)(b * Ln + g * 64 + r) * Dn + d]);
    part[(size_t)blk * Dn + d] = s;
}
__global__ __launch_bounds__(256) void mean_final_k(const float* __restrict__ part,
                                                    float* __restrict__ out) {
    int b = blockIdx.x, d = threadIdx.x;
    float s = 0.f;
#pragma unroll
    for (int g = 0; g < 16; ++g) s += part[(size_t)(b * 16 + g) * Dn + d];
    out[b * Dn + d] = s * (1.0f / (float)Ln);
}

// ---------------------------------------------------------------------------
extern "C" void kernel_launch(void* const* d_in, const int* in_sizes, int n_in,
                              void* d_out, int out_size, void* d_ws, size_t ws_size,
                              hipStream_t stream) {
    const float* x    = (const float*)d_in[0];
    const float* emb  = (const float*)d_in[1];
    const float* Wq   = (const float*)d_in[2];
    const float* bq   = (const float*)d_in[3];
    const float* Wk   = (const float*)d_in[4];
    const float* bk   = (const float*)d_in[5];
    const float* Wv   = (const float*)d_in[6];
    const float* bv   = (const float*)d_in[7];
    const float* Wo   = (const float*)d_in[8];
    const float* bo   = (const float*)d_in[9];
    const float* rk   = (const float*)d_in[10];
    const float* rb   = (const float*)d_in[11];
    const float* ln1g = (const float*)d_in[12];
    const float* ln1b = (const float*)d_in[13];
    const float* W1   = (const float*)d_in[14];
    const float* b1   = (const float*)d_in[15];
    const float* W2   = (const float*)d_in[16];
    const float* b2   = (const float*)d_in[17];
    const float* ln2g = (const float*)d_in[18];
    const float* ln2b = (const float*)d_in[19];

    float* out = (float*)d_out;
    float* avg = out + Bn * Dn;

    char* ws = (char*)d_ws;
    const size_t MB = 1024 * 1024;
    ushort* hb   = (ushort*)(ws);             // 2 MB
    ushort* qkvb = (ushort*)(ws + 2 * MB);    // 6 MB
    ushort* ctxb = (ushort*)(ws + 8 * MB);    // 2 MB
    ushort* t1   = (ushort*)(ws + 10 * MB);   // 2 MB
    ushort* ffb  = (ushort*)(ws + 12 * MB);   // 8 MB
    ushort* qkvT = (ushort*)(ws + 20 * MB);   // 1.5 MB
    ushort* WoT  = (ushort*)(ws + 22 * MB);   // 0.5 MB
    ushort* W1T  = (ushort*)(ws + 23 * MB);   // 2 MB
    ushort* W2T  = (ushort*)(ws + 25 * MB);   // 2 MB
    float*  bqkv = (float*)(ws + 27 * MB);
    float*  bkT  = (float*)(ws + 27 * MB + 65536);
    float*  bbT  = (float*)(ws + 27 * MB + 131072);
    ushort* Vt   = (ushort*)(ws + 30 * MB);   // 2 MB
    float*  mpart= (float*)(ws + 33 * MB);    // 64 KB
    ushort* Pbuf = (ushort*)(ws + 36 * MB);   // 3 x 32 MB (mode 1/2)
    float*  fpart= (float*)(ws + 132 * MB);   // 16 MB (FF2 split-K partials)

    const size_t need = 132 * MB + (size_t)4 * NTOK * Dn * sizeof(float);
    const bool fancy = (ws_size >= need);

    embed_k<<<NTOK, 256, 0, stream>>>(x, emb, hb);
    relbias_k<<<64, 256, 0, stream>>>(rk, rb, bkT, bbT);
    prep_bias<<<12, 256, 0, stream>>>(bq, bk, bv, bqkv);

    dim3 t88(8, 8, NLn);
    transpose_cvt<<<t88, 256, 0, stream>>>(Wq, qkvT + 0,      256, 256, 65536, 196608);
    transpose_cvt<<<t88, 256, 0, stream>>>(Wk, qkvT + 65536,  256, 256, 65536, 196608);
    transpose_cvt<<<t88, 256, 0, stream>>>(Wv, qkvT + 131072, 256, 256, 65536, 196608);
    transpose_cvt<<<t88, 256, 0, stream>>>(Wo, WoT,           256, 256, 65536, 65536);
    transpose_cvt<<<dim3(32, 8, NLn), 256, 0, stream>>>(W1, W1T, 256, 1024, 262144, 262144);
    transpose_cvt<<<dim3(8, 32, NLn), 256, 0, stream>>>(W2, W2T, 1024, 256, 262144, 262144);

    for (int l = 0; l < NLn; ++l) {
        if (fancy) {
            if (l == 0) {
                gemm128<0, 1><<<dim3(6, 32), 512, 0, stream>>>(
                    hb, qkvT + (size_t)l * 196608, bqkv + l * QKVW, qkvb, nullptr,
                    NTOK, QKVW, Dn, 0, nullptr, nullptr, Vt);
            } else {
                gemm128<1, 1><<<dim3(6, 32), 512, 0, stream>>>(
                    hb, qkvT + (size_t)l * 196608, bqkv + l * QKVW, qkvb, nullptr,
                    NTOK, QKVW, Dn, 0, ln2g + (l - 1) * 256, ln2b + (l - 1) * 256, Vt);
            }
            if (l < 3) {
                attn_fused<1><<<1024, 1024, 0, stream>>>(
                    qkvb, Vt, bkT + l * Hn * Ln, bbT + l * Hn * Ln, ctxb, avg,
                    Pbuf + (size_t)l * PELEMS, 0);
            } else {
                attn_fused<2><<<1024, 1024, 0, stream>>>(
                    qkvb, Vt, bkT + l * Hn * Ln, bbT + l * Hn * Ln, ctxb, avg,
                    Pbuf, 0);
            }
            gemm_mfma<0><<<dim3(4, 64), 256, 0, stream>>>(
                ctxb, WoT + (size_t)l * 65536, bo + l * 256, t1,
                NTOK, Dn, Dn, 0, nullptr, nullptr, nullptr);
            gemm128<1, 1><<<dim3(8, 32), 512, 0, stream>>>(
                t1, W1T + (size_t)l * 262144, b1 + l * FFn, ffb, nullptr,
                NTOK, FFn, Dn, 1, ln1g + l * 256, ln1b + l * 256, nullptr);
            gemm128<0, 4><<<dim3(2, 32, 4), 512, 0, stream>>>(
                ffb, W2T + (size_t)l * 262144, nullptr, nullptr, fpart,
                NTOK, Dn, FFn, 0, nullptr, nullptr, nullptr);
            combine_k<<<1024, 256, 0, stream>>>(fpart, b2 + l * 256, hb);
        } else {
            if (l == 0) {
                gemm_mfma<0><<<dim3(12, 64), 256, 0, stream>>>(
                    hb, qkvT + (size_t)l * 196608, bqkv + l * QKVW, qkvb,
                    NTOK, QKVW, Dn, 0, nullptr, nullptr, Vt);
            } else {
                gemm_mfma<1><<<dim3(12, 64), 256, 0, stream>>>(
                    hb, qkvT + (size_t)l * 196608, bqkv + l * QKVW, qkvb,
                    NTOK, QKVW, Dn, 0, ln2g + (l - 1) * 256, ln2b + (l - 1) * 256, Vt);
            }
            attn_fused<0><<<1024, 1024, 0, stream>>>(
                qkvb, Vt, bkT + l * Hn * Ln, bbT + l * Hn * Ln, ctxb, avg,
                (ushort*)Pbuf, (l == 0) ? 1 : 0);
            gemm_mfma<0><<<dim3(4, 64), 256, 0, stream>>>(
                ctxb, WoT + (size_t)l * 65536, bo + l * 256, t1,
                NTOK, Dn, Dn, 0, nullptr, nullptr, nullptr);
            gemm_mfma<1><<<dim3(16, 64), 256, 0, stream>>>(
                t1, W1T + (size_t)l * 262144, b1 + l * FFn, ffb,
                NTOK, FFn, Dn, 1, ln1g + l * 256, ln1b + l * 256, nullptr);
            gemm_mfma<0><<<dim3(4, 64), 256, 0, stream>>>(
                ffb, W2T + (size_t)l * 262144, b2 + l * 256, hb,
                NTOK, Dn, FFn, 0, nullptr, nullptr, nullptr);
        }
    }
    // final ln2 (layer 3) before the mean
    layernorm_k<<<NTOK / 4, 256, 0, stream>>>(
        hb, ln2g + 3 * 256, ln2b + 3 * 256, hb);
    mean_part_k<<<64, 256, 0, stream>>>(hb, mpart);
    mean_final_k<<<Bn, 256, 0, stream>>>(mpart, out);
}

// Round 17
// 374.427 us; speedup vs baseline: 1.0947x; 1.0947x over previous
//
#include <hip/hip_runtime.h>
#include <hip/hip_bf16.h>
#include <math.h>

// Problem constants
#define Bn 4
#define Ln 1024
#define Vn 64
#define Dn 256
#define Hn 4
#define DKn 64
#define NLn 4
#define Mn 20
#define FFn 1024
#define NTOK (Bn * Ln)   // 4096
#define QKVW 768         // fused q|k|v width
#define LOG2E 1.4426950408889634f
#define PELEMS (Bn * Hn * Ln * Ln)   // 16777216 elements per layer P

typedef __attribute__((ext_vector_type(8))) short bf16x8;
typedef __attribute__((ext_vector_type(4))) float f32x4;

__device__ __forceinline__ ushort f2b(float f) {   // fp32 -> bf16 RNE
    uint u = __float_as_uint(f);
    u += 0x7fff + ((u >> 16) & 1);
    return (ushort)(u >> 16);
}
__device__ __forceinline__ float b2f(ushort u) {   // exact
    return __uint_as_float(((uint)u) << 16);
}

// ---------------------------------------------------------------------------
__global__ __launch_bounds__(256) void embed_k(const float* __restrict__ X,
                                               const float* __restrict__ E,
                                               ushort* __restrict__ Hb) {
    __shared__ float xs[Vn];
    int n = blockIdx.x, d = threadIdx.x;
    if (threadIdx.x < Vn) xs[threadIdx.x] = X[n * Vn + threadIdx.x];
    __syncthreads();
    float s = 0.f;
#pragma unroll
    for (int v = 0; v < Vn; ++v) s += xs[v] * E[v * Dn + d];
    Hb[(size_t)n * Dn + d] = f2b(s);
}

// ---------------------------------------------------------------------------
// bias tables, pre-scaled into exp2 domain
__global__ __launch_bounds__(256) void relbias_k(const float* __restrict__ rk,
                                                 const float* __restrict__ rb,
                                                 float* __restrict__ bkT,
                                                 float* __restrict__ bbT) {
    int tid = blockIdx.x * 256 + threadIdx.x;   // < NL*H*1024
    int dist = tid & 1023;
    int hh = (tid >> 10) & 3;
    int l = tid >> 12;
    float dd = (float)dist;
    if (dist > Mn) dd = (float)Mn + log2f((float)(dist - Mn));
    if (dd > 2.0f * Mn) dd = 2.0f * Mn;
    int idx = (int)dd;
    bkT[tid] = rk[(l * (2 * Mn + 1) + idx) * Hn + hh] * 0.125f * LOG2E;
    bbT[tid] = rb[(l * (2 * Mn + 1) + idx) * Hn + hh] * LOG2E;
}

// ---------------------------------------------------------------------------
__global__ __launch_bounds__(256) void prep_bias(const float* __restrict__ bq,
                                                 const float* __restrict__ bk,
                                                 const float* __restrict__ bv,
                                                 float* __restrict__ bqkv) {
    int idx = blockIdx.x * 256 + threadIdx.x;   // < NL*768
    int l = idx / QKVW, r = idx - l * QKVW;
    float v;
    if (r < 256)      v = bq[l * 256 + r];
    else if (r < 512) v = bk[l * 256 + r - 256];
    else              v = bv[l * 256 + r - 512];
    bqkv[idx] = v;
}

// ---------------------------------------------------------------------------
// Weight transpose + fp32->bf16: dst[c][r] = src[r][c]; grid.z = layer.
__global__ __launch_bounds__(256) void transpose_cvt(
    const float* __restrict__ src, ushort* __restrict__ dst,
    int R, int C, int srcLS, int dstLS) {
    __shared__ float s[32][33];
    src += (size_t)blockIdx.z * srcLS;
    dst += (size_t)blockIdx.z * dstLS;
    int r0 = blockIdx.y * 32, c0 = blockIdx.x * 32;
    int tx = threadIdx.x & 31, ty = threadIdx.x >> 5;
#pragma unroll
    for (int ii = 0; ii < 4; ++ii)
        s[ty + 8 * ii][tx] = src[(size_t)(r0 + ty + 8 * ii) * C + c0 + tx];
    __syncthreads();
#pragma unroll
    for (int ii = 0; ii < 4; ++ii)
        dst[(size_t)(c0 + ty + 8 * ii) * R + r0 + tx] = f2b(s[tx][ty + 8 * ii]);
}

// ---------------------------------------------------------------------------
// bf16 MFMA GEMM, BK=64 (half the barriers of BK=32).
// C[m][n] = act(sum_k LN?(A)[m][k]*Bt[n][k] + bias[n]), C bf16.
// LNA=1: LayerNorm(A row) fused into A staging (requires K==256).
// Vt_out: if non-null, blocks with nBase>=512 write transposed into Vt.
#define GST 72   // ushort stride per LDS row (144B)
#define GEMM_KK_MFMA(KK)                                                      \
    {                                                                         \
        bf16x8 a0 = *(const bf16x8*)&As[(wm * 32 + l15) * GST + (KK)*32 + lg * 8];      \
        bf16x8 a1 = *(const bf16x8*)&As[(wm * 32 + 16 + l15) * GST + (KK)*32 + lg * 8]; \
        bf16x8 b0 = *(const bf16x8*)&Bs[(wn * 32 + l15) * GST + (KK)*32 + lg * 8];      \
        bf16x8 b1 = *(const bf16x8*)&Bs[(wn * 32 + 16 + l15) * GST + (KK)*32 + lg * 8]; \
        acc[0][0] = __builtin_amdgcn_mfma_f32_16x16x32_bf16(a0, b0, acc[0][0], 0, 0, 0); \
        acc[0][1] = __builtin_amdgcn_mfma_f32_16x16x32_bf16(a0, b1, acc[0][1], 0, 0, 0); \
        acc[1][0] = __builtin_amdgcn_mfma_f32_16x16x32_bf16(a1, b0, acc[1][0], 0, 0, 0); \
        acc[1][1] = __builtin_amdgcn_mfma_f32_16x16x32_bf16(a1, b1, acc[1][1], 0, 0, 0); \
    }

template <int LNA>
__global__ __launch_bounds__(256) void gemm_mfma(
    const ushort* __restrict__ A, const ushort* __restrict__ Bt,
    const float* __restrict__ bias, ushort* __restrict__ C,
    int M, int N, int K, int act,
    const float* __restrict__ lng, const float* __restrict__ lnb,
    ushort* __restrict__ Vt_out) {
    __shared__ __align__(16) ushort As[64 * GST];
    __shared__ __align__(16) ushort Bs[64 * GST];
    __shared__ float gl[256];
    __shared__ float bl[256];
    int t = threadIdx.x;
    int lane = t & 63, w = t >> 6;
    int wm = w >> 1, wn = w & 1;
    int l15 = lane & 15, lg = lane >> 4;
    int mBase = blockIdx.y * 64, nBase = blockIdx.x * 64;
    int lrow = t >> 2, lkc = (t & 3) * 16;   // 4 threads x 16 ushorts = 64 k
    const ushort* Ap = A + (size_t)(mBase + lrow) * K + lkc;
    const ushort* Bp = Bt + (size_t)(nBase + lrow) * K + lkc;
    f32x4 acc[2][2] = {};

    if constexpr (LNA) {
        // K == 256: preload the thread's 64 A elements (8 x uint4)
        uint4 areg[8];
        float s = 0.f;
#pragma unroll
        for (int kc = 0; kc < 4; ++kc)
#pragma unroll
            for (int h = 0; h < 2; ++h) {
                areg[kc * 2 + h] = *(const uint4*)(Ap + kc * 64 + h * 8);
                const ushort* e = (const ushort*)&areg[kc * 2 + h];
#pragma unroll
                for (int q = 0; q < 8; ++q) s += b2f(e[q]);
            }
        s += __shfl_xor(s, 1, 64);
        s += __shfl_xor(s, 2, 64);
        float mu = s * (1.0f / 256.0f);
        float vv = 0.f;
#pragma unroll
        for (int kc = 0; kc < 8; ++kc) {
            const ushort* e = (const ushort*)&areg[kc];
#pragma unroll
            for (int q = 0; q < 8; ++q) {
                float d = b2f(e[q]) - mu;
                vv += d * d;
            }
        }
        vv += __shfl_xor(vv, 1, 64);
        vv += __shfl_xor(vv, 2, 64);
        float rs = rsqrtf(vv * (1.0f / 256.0f) + 1e-5f);
        gl[t] = lng[t];
        bl[t] = lnb[t];
        __syncthreads();
#pragma unroll
        for (int kc = 0; kc < 4; ++kc) {
            uint4 bv0 = *(const uint4*)(Bp + kc * 64);
            uint4 bv1 = *(const uint4*)(Bp + kc * 64 + 8);
            __syncthreads();
#pragma unroll
            for (int h = 0; h < 2; ++h) {
                const ushort* e = (const ushort*)&areg[kc * 2 + h];
                ushort outv[8];
#pragma unroll
                for (int q = 0; q < 8; ++q) {
                    int col = kc * 64 + lkc + h * 8 + q;
                    outv[q] = f2b((b2f(e[q]) - mu) * rs * gl[col] + bl[col]);
                }
                *(uint4*)&As[lrow * GST + lkc + h * 8] = *(const uint4*)outv;
            }
            *(uint4*)&Bs[lrow * GST + lkc] = bv0;
            *(uint4*)&Bs[lrow * GST + lkc + 8] = bv1;
            __syncthreads();
            GEMM_KK_MFMA(0)
            GEMM_KK_MFMA(1)
        }
    } else {
        for (int k0 = 0; k0 < K; k0 += 64) {
            uint4 av0 = *(const uint4*)(Ap + k0);
            uint4 av1 = *(const uint4*)(Ap + k0 + 8);
            uint4 bv0 = *(const uint4*)(Bp + k0);
            uint4 bv1 = *(const uint4*)(Bp + k0 + 8);
            __syncthreads();
            *(uint4*)&As[lrow * GST + lkc] = av0;
            *(uint4*)&As[lrow * GST + lkc + 8] = av1;
            *(uint4*)&Bs[lrow * GST + lkc] = bv0;
            *(uint4*)&Bs[lrow * GST + lkc + 8] = bv1;
            __syncthreads();
            GEMM_KK_MFMA(0)
            GEMM_KK_MFMA(1)
        }
    }
    if (Vt_out != nullptr && nBase >= 512) {
        // V section: write transposed to Vt[((b*4+hh)*64+dd)][token]
#pragma unroll
        for (int ni = 0; ni < 2; ++ni) {
            int col = nBase + wn * 32 + ni * 16 + l15;
            float bc = bias[col];
            int d = col - 512;
#pragma unroll
            for (int mi = 0; mi < 2; ++mi) {
                int rb = mBase + wm * 32 + mi * 16 + lg * 4;
                int bb_ = rb >> 10, i_ = rb & 1023;
                size_t vb = ((size_t)(bb_ * 4 + (d >> 6)) * 64 + (d & 63)) * Ln + i_;
                ushort o4[4];
#pragma unroll
                for (int j = 0; j < 4; ++j) o4[j] = f2b(acc[mi][ni][j] + bc);
                *(ushort4*)&Vt_out[vb] = *(const ushort4*)o4;
            }
        }
        return;
    }
#pragma unroll
    for (int ni = 0; ni < 2; ++ni) {
        int col = nBase + wn * 32 + ni * 16 + l15;
        float bc = bias[col];
#pragma unroll
        for (int mi = 0; mi < 2; ++mi) {
            int rb = mBase + wm * 32 + mi * 16 + lg * 4;
#pragma unroll
            for (int j = 0; j < 4; ++j) {
                float v = acc[mi][ni][j] + bc;
                if (act) v = v * 0.5f * (1.0f + erff(v * 0.7071067811865475f));
                C[(size_t)(rb + j) * N + col] = f2b(v);
            }
        }
    }
}

// ---------------------------------------------------------------------------
// MFMA flash attention, 8 waves, ~29.7KB LDS -> 4 blocks/CU. Pw/Opart alias.
// MODE 0: f32 RMW into avg (fallback). MODE 1: stream P bf16 to Pout in
// TILE-LINEAR layout (512B coalesced per wave instr). MODE 2 (last layer):
// read P0..P2 tile-linear + own P, write final avg f32.
#define PWST 40   // ushort stride per P row (80B, 16B-aligned)
#define NW 8
template <int MODE>
__global__ __launch_bounds__(512) void attn_fused(
    const ushort* __restrict__ qkv, const ushort* __restrict__ Vt,
    const float* __restrict__ bkTab, const float* __restrict__ bbTab,
    ushort* __restrict__ ctx, float* __restrict__ avg,
    ushort* __restrict__ Pout, int first) {
    __shared__ float bk_l[Ln];
    __shared__ float bb_l[Ln];
    __shared__ __align__(16) char uni[20480];   // Pw: 8x2560 | Opart: 4x4096
    __shared__ float mm[NW][16];
    __shared__ float ll[NW][16];

    int t = threadIdx.x;
    int lane = t & 63, w = t >> 6;        // w in [0,8)
    int wn = w & 3, wc = w >> 2;          // col slice, chunk half
    int l15 = lane & 15, lg = lane >> 4;

    ushort* pwh = (ushort*)&uni[w * 2560];          // [16*PWST] P hi
    ushort* pwl = (ushort*)&uni[w * 2560 + 1280];   // [16*PWST] P lo

    int bid = blockIdx.x;
    int xcd = bid & 7, sub = bid >> 3;    // sub in [0,128)
    int bh = xcd * 2 + (sub >> 6);
    int q = sub & 63;
    int b = bh >> 2, hh = bh & 3;
    int i0 = q * 16;

#pragma unroll
    for (int ii = 0; ii < 2; ++ii) {
        bk_l[t + 512 * ii] = bkTab[hh * Ln + t + 512 * ii];
        bb_l[t + 512 * ii] = bbTab[hh * Ln + t + 512 * ii];
    }
    __syncthreads();

    // Q fragment (A-operand): row = i0 + l15, k = lg*8 (+32)
    bf16x8 qa0, qa1;
    {
        const ushort* qp = qkv + (size_t)(b * Ln + i0 + l15) * QKVW + hh * DKn;
        qa0 = *(const bf16x8*)(qp + lg * 8);
        qa1 = *(const bf16x8*)(qp + 32 + lg * 8);
    }

    const ushort* kbase = qkv + (size_t)(b * Ln) * QKVW + Dn + hh * DKn;

    // ---- QK pass over this wave's 8 chunks (barrier-free) -------------------
    f32x4 sv[8];
    float m[4] = {-1e30f, -1e30f, -1e30f, -1e30f};
#pragma unroll
    for (int cl = 0; cl < 8; ++cl) {
        int c = wc * 8 + cl;
        const ushort* kp = kbase + (size_t)(c * 64 + wn * 16 + l15) * QKVW;
        bf16x8 k0 = *(const bf16x8*)(kp + lg * 8);
        bf16x8 k1 = *(const bf16x8*)(kp + 32 + lg * 8);
        f32x4 acc = {};
        acc = __builtin_amdgcn_mfma_f32_16x16x32_bf16(qa0, k0, acc, 0, 0, 0);
        acc = __builtin_amdgcn_mfma_f32_16x16x32_bf16(qa1, k1, acc, 0, 0, 0);
        int j = c * 64 + wn * 16 + l15;
#pragma unroll
        for (int r = 0; r < 4; ++r) {
            int i = i0 + lg * 4 + r;
            int dist = (i > j) ? (i - j) : (j - i);
            float s = acc[r] * bk_l[dist] + bb_l[dist];
            sv[cl][r] = s;
            m[r] = fmaxf(m[r], s);
        }
    }
    // merge max over the 16 l15-lanes
#pragma unroll
    for (int mask = 1; mask < 16; mask <<= 1)
#pragma unroll
        for (int r = 0; r < 4; ++r) m[r] = fmaxf(m[r], __shfl_xor(m[r], mask, 64));
    // merge max across the 8 waves
    if (l15 == 0)
#pragma unroll
        for (int r = 0; r < 4; ++r) mm[w][lg * 4 + r] = m[r];
    __syncthreads();
#pragma unroll
    for (int r = 0; r < 4; ++r) {
        int row = lg * 4 + r;
        float m0 = fmaxf(fmaxf(mm[0][row], mm[1][row]), fmaxf(mm[2][row], mm[3][row]));
        float m1 = fmaxf(fmaxf(mm[4][row], mm[5][row]), fmaxf(mm[6][row], mm[7][row]));
        m[r] = fmaxf(m0, m1);
    }
    // p_unnorm = exp2(s - m); row sums
    float lsum[4] = {0.f, 0.f, 0.f, 0.f};
#pragma unroll
    for (int cl = 0; cl < 8; ++cl)
#pragma unroll
        for (int r = 0; r < 4; ++r) {
            float p = exp2f(sv[cl][r] - m[r]);
            sv[cl][r] = p;
            lsum[r] += p;
        }
#pragma unroll
    for (int mask = 1; mask < 16; mask <<= 1)
#pragma unroll
        for (int r = 0; r < 4; ++r) lsum[r] += __shfl_xor(lsum[r], mask, 64);
    if (l15 == 0)
#pragma unroll
        for (int r = 0; r < 4; ++r) ll[w][lg * 4 + r] = lsum[r];
    __syncthreads();
    float invl[4];
#pragma unroll
    for (int r = 0; r < 4; ++r) {
        int row = lg * 4 + r;
        invl[r] = 1.0f / (ll[0][row] + ll[1][row] + ll[2][row] + ll[3][row] +
                          ll[4][row] + ll[5][row] + ll[6][row] + ll[7][row]);
    }

    // ---- PV partial-O + P/avg output: ZERO barriers --------------------------
    const ushort* vbase = Vt + (size_t)bh * DKn * Ln;       // [64 d][Ln k]
    float* avgrow = avg + ((size_t)bh * Ln + i0) * Ln;      // MODE 0
    int iw = lane >> 2, jq = lane & 3;                      // P tile map
    f32x4 acco[4] = {};
#pragma unroll
    for (int p = 0; p < 4; ++p) {
        const int c0 = wc * 8 + 2 * p, c1 = c0 + 1;
        float aold[2][4];
        if (MODE == 0 && !first) {
#pragma unroll
            for (int cc = 0; cc < 2; ++cc)
#pragma unroll
                for (int r = 0; r < 4; ++r)
                    aold[cc][r] = avgrow[(size_t)(lg * 4 + r) * Ln +
                                         (c0 + cc) * 64 + wn * 16 + l15];
        }
        // stage P (hi/lo) into wave-private LDS
#pragma unroll
        for (int cc = 0; cc < 2; ++cc)
#pragma unroll
            for (int r = 0; r < 4; ++r) {
                float pv = sv[2 * p + cc][r] * invl[r];
                sv[2 * p + cc][r] = pv;
                ushort ph = f2b(pv);
                int off = (lg * 4 + r) * PWST + cc * 16 + l15;
                pwh[off] = ph;
                pwl[off] = f2b(pv - b2f(ph));
            }
        // V A-fragments
        int kcol = (lg < 2 ? c0 : c1) * 64 + wn * 16 + (lg & 1) * 8;
        bf16x8 va0 = *(const bf16x8*)(vbase + (size_t)(0 * 16 + l15) * Ln + kcol);
        bf16x8 va1 = *(const bf16x8*)(vbase + (size_t)(1 * 16 + l15) * Ln + kcol);
        bf16x8 va2 = *(const bf16x8*)(vbase + (size_t)(2 * 16 + l15) * Ln + kcol);
        bf16x8 va3 = *(const bf16x8*)(vbase + (size_t)(3 * 16 + l15) * Ln + kcol);
        // B fragments from own LDS (same-wave RAW: compiler lgkmcnt)
        bf16x8 pbh = *(const bf16x8*)&pwh[l15 * PWST + lg * 8];
        bf16x8 pbl = *(const bf16x8*)&pwl[l15 * PWST + lg * 8];
        acco[0] = __builtin_amdgcn_mfma_f32_16x16x32_bf16(va0, pbh, acco[0], 0, 0, 0);
        acco[1] = __builtin_amdgcn_mfma_f32_16x16x32_bf16(va1, pbh, acco[1], 0, 0, 0);
        acco[2] = __builtin_amdgcn_mfma_f32_16x16x32_bf16(va2, pbh, acco[2], 0, 0, 0);
        acco[3] = __builtin_amdgcn_mfma_f32_16x16x32_bf16(va3, pbh, acco[3], 0, 0, 0);
        acco[0] = __builtin_amdgcn_mfma_f32_16x16x32_bf16(va0, pbl, acco[0], 0, 0, 0);
        acco[1] = __builtin_amdgcn_mfma_f32_16x16x32_bf16(va1, pbl, acco[1], 0, 0, 0);
        acco[2] = __builtin_amdgcn_mfma_f32_16x16x32_bf16(va2, pbl, acco[2], 0, 0, 0);
        acco[3] = __builtin_amdgcn_mfma_f32_16x16x32_bf16(va3, pbl, acco[3], 0, 0, 0);
        if (MODE == 0) {
#pragma unroll
            for (int cc = 0; cc < 2; ++cc)
#pragma unroll
                for (int r = 0; r < 4; ++r) {
                    float v = 0.25f * sv[2 * p + cc][r];
                    if (!first) v += aold[cc][r];
                    avgrow[(size_t)(lg * 4 + r) * Ln + (c0 + cc) * 64 + wn * 16 + l15] = v;
                }
        } else if (MODE == 1) {
            // tile-linear P store: 512B contiguous per wave per cc
            size_t tb = ((((size_t)bid * 8 + w) * 4 + p) * 2) * 256 + (size_t)lane * 4;
            ushort4 ph0 = *(const ushort4*)&pwh[iw * PWST + 0 * 16 + jq * 4];
            ushort4 ph1 = *(const ushort4*)&pwh[iw * PWST + 1 * 16 + jq * 4];
            *(ushort4*)&Pout[tb] = ph0;
            *(ushort4*)&Pout[tb + 256] = ph1;
        } else {
            // MODE 2: read P0..P2 tile-linear, add own P, write avg f32
#pragma unroll
            for (int cc = 0; cc < 2; ++cc) {
                int c = c0 + cc;
                size_t tb = ((((size_t)bid * 8 + w) * 4 + p) * 2 + cc) * 256 +
                            (size_t)lane * 4;
                ushort4 p0 = *(const ushort4*)&Pout[tb];
                ushort4 p1 = *(const ushort4*)&Pout[(size_t)PELEMS + tb];
                ushort4 p2 = *(const ushort4*)&Pout[(size_t)2 * PELEMS + tb];
                ushort4 p3 = *(const ushort4*)&pwh[iw * PWST + cc * 16 + jq * 4];
                const ushort* q0 = (const ushort*)&p0;
                const ushort* q1 = (const ushort*)&p1;
                const ushort* q2 = (const ushort*)&p2;
                const ushort* q3 = (const ushort*)&p3;
                size_t base = ((size_t)(bh * Ln) + i0 + iw) * Ln +
                              c * 64 + wn * 16 + jq * 4;
                float4 o;
                float* op_ = (float*)&o;
#pragma unroll
                for (int k = 0; k < 4; ++k)
                    op_[k] = 0.25f * (b2f(q0[k]) + b2f(q1[k]) + b2f(q2[k]) + b2f(q3[k]));
                *(float4*)&avg[base] = o;
            }
        }
    }

    // ---- reduce partial O across 8 waves (Opart aliases Pw) ------------------
    __syncthreads();   // all PV done; Pw region dead
    {
        float* op = (float*)&uni[wn * 4096];
        if (wc == 1) {
#pragma unroll
            for (int dg = 0; dg < 4; ++dg)
#pragma unroll
                for (int r = 0; r < 4; ++r)
                    op[(dg * 16 + lg * 4 + r) * 16 + l15] = acco[dg][r];
        }
    }
    __syncthreads();
    {
        float* op = (float*)&uni[wn * 4096];
        if (wc == 0) {
#pragma unroll
            for (int dg = 0; dg < 4; ++dg)
#pragma unroll
                for (int r = 0; r < 4; ++r)
                    op[(dg * 16 + lg * 4 + r) * 16 + l15] += acco[dg][r];
        }
    }
    __syncthreads();
#pragma unroll
    for (int k = 0; k < 2; ++k) {
        int idx = t + 512 * k;          // idx = d*16 + i
        float v = ((const float*)&uni[0])[idx] + ((const float*)&uni[4096])[idx] +
                  ((const float*)&uni[8192])[idx] + ((const float*)&uni[12288])[idx];
        int dd = idx >> 4, ii = idx & 15;
        ctx[(size_t)(b * Ln + i0 + ii) * Dn + hh * DKn + dd] = f2b(v);
    }
}

// ---------------------------------------------------------------------------
__global__ __launch_bounds__(256) void layernorm_k(const ushort* __restrict__ X,
                                                   const float* __restrict__ g,
                                                   const float* __restrict__ bta,
                                                   ushort* __restrict__ Y) {
    int w = threadIdx.x >> 6, lane = threadIdx.x & 63;
    int row = blockIdx.x * 4 + w;
    const ushort* xr = X + (size_t)row * Dn;
    float x[4];
#pragma unroll
    for (int ii = 0; ii < 4; ++ii) x[ii] = b2f(xr[lane + 64 * ii]);
    float s = x[0] + x[1] + x[2] + x[3];
#pragma unroll
    for (int m = 1; m < 64; m <<= 1) s += __shfl_xor(s, m, 64);
    float mu = s * (1.0f / 256.0f);
    float vs = 0.f;
#pragma unroll
    for (int ii = 0; ii < 4; ++ii) {
        float d = x[ii] - mu;
        vs += d * d;
    }
#pragma unroll
    for (int m = 1; m < 64; m <<= 1) vs += __shfl_xor(vs, m, 64);
    float rs = rsqrtf(vs * (1.0f / 256.0f) + 1e-5f);
#pragma unroll
    for (int ii = 0; ii < 4; ++ii) {
        int d = lane + 64 * ii;
        Y[(size_t)row * Dn + d] = f2b((x[ii] - mu) * rs * g[d] + bta[d]);
    }
}

// ---------------------------------------------------------------------------
__global__ __launch_bounds__(256) void mean_part_k(const ushort* __restrict__ Hb,
                                                   float* __restrict__ part) {
    int blk = blockIdx.x;            // 64 = 4 b x 16 groups
    int b = blk >> 4, g = blk & 15;
    int d = threadIdx.x;
    float s = 0.f;
#pragma unroll
    for (int r = 0; r < 64; ++r)
        s += b2f(Hb[(size_t)(b * Ln + g * 64 + r) * Dn + d]);
    part[(size_t)blk * Dn + d] = s;
}
__global__ __launch_bounds__(256) void mean_final_k(const float* __restrict__ part,
                                                    float* __restrict__ out) {
    int b = blockIdx.x, d = threadIdx.x;
    float s = 0.f;
#pragma unroll
    for (int g = 0; g < 16; ++g) s += part[(size_t)(b * 16 + g) * Dn + d];
    out[b * Dn + d] = s * (1.0f / (float)Ln);
}

// ---------------------------------------------------------------------------
extern "C" void kernel_launch(void* const* d_in, const int* in_sizes, int n_in,
                              void* d_out, int out_size, void* d_ws, size_t ws_size,
                              hipStream_t stream) {
    const float* x    = (const float*)d_in[0];
    const float* emb  = (const float*)d_in[1];
    const float* Wq   = (const float*)d_in[2];
    const float* bq   = (const float*)d_in[3];
    const float* Wk   = (const float*)d_in[4];
    const float* bk   = (const float*)d_in[5];
    const float* Wv   = (const float*)d_in[6];
    const float* bv   = (const float*)d_in[7];
    const float* Wo   = (const float*)d_in[8];
    const float* bo   = (const float*)d_in[9];
    const float* rk   = (const float*)d_in[10];
    const float* rb   = (const float*)d_in[11];
    const float* ln1g = (const float*)d_in[12];
    const float* ln1b = (const float*)d_in[13];
    const float* W1   = (const float*)d_in[14];
    const float* b1   = (const float*)d_in[15];
    const float* W2   = (const float*)d_in[16];
    const float* b2   = (const float*)d_in[17];
    const float* ln2g = (const float*)d_in[18];
    const float* ln2b = (const float*)d_in[19];

    float* out = (float*)d_out;
    float* avg = out + Bn * Dn;

    char* ws = (char*)d_ws;
    const size_t MB = 1024 * 1024;
    ushort* hb   = (ushort*)(ws);             // 2 MB
    ushort* qkvb = (ushort*)(ws + 2 * MB);    // 6 MB
    ushort* ctxb = (ushort*)(ws + 8 * MB);    // 2 MB
    ushort* t1   = (ushort*)(ws + 10 * MB);   // 2 MB
    ushort* ffb  = (ushort*)(ws + 12 * MB);   // 8 MB
    ushort* qkvT = (ushort*)(ws + 20 * MB);   // 1.5 MB
    ushort* WoT  = (ushort*)(ws + 22 * MB);   // 0.5 MB
    ushort* W1T  = (ushort*)(ws + 23 * MB);   // 2 MB
    ushort* W2T  = (ushort*)(ws + 25 * MB);   // 2 MB
    float*  bqkv = (float*)(ws + 27 * MB);
    float*  bkT  = (float*)(ws + 27 * MB + 65536);
    float*  bbT  = (float*)(ws + 27 * MB + 131072);
    ushort* Vt   = (ushort*)(ws + 30 * MB);   // 2 MB
    float*  mpart= (float*)(ws + 33 * MB);    // 64 KB
    ushort* Pbuf = (ushort*)(ws + 36 * MB);   // 3 x 32 MB used (mode 1/2)

    const size_t need = 36 * MB + (size_t)3 * PELEMS * sizeof(ushort);
    const bool fancy = (ws_size >= need);

    embed_k<<<NTOK, 256, 0, stream>>>(x, emb, hb);
    relbias_k<<<64, 256, 0, stream>>>(rk, rb, bkT, bbT);
    prep_bias<<<12, 256, 0, stream>>>(bq, bk, bv, bqkv);

    dim3 t88(8, 8, NLn);
    transpose_cvt<<<t88, 256, 0, stream>>>(Wq, qkvT + 0,      256, 256, 65536, 196608);
    transpose_cvt<<<t88, 256, 0, stream>>>(Wk, qkvT + 65536,  256, 256, 65536, 196608);
    transpose_cvt<<<t88, 256, 0, stream>>>(Wv, qkvT + 131072, 256, 256, 65536, 196608);
    transpose_cvt<<<t88, 256, 0, stream>>>(Wo, WoT,           256, 256, 65536, 65536);
    transpose_cvt<<<dim3(32, 8, NLn), 256, 0, stream>>>(W1, W1T, 256, 1024, 262144, 262144);
    transpose_cvt<<<dim3(8, 32, NLn), 256, 0, stream>>>(W2, W2T, 1024, 256, 262144, 262144);

    for (int l = 0; l < NLn; ++l) {
        // QKV projection (V written transposed into Vt via epilogue);
        // layers 1..3 fuse previous layer's ln2 into A.
        if (l == 0) {
            gemm_mfma<0><<<dim3(12, 64), 256, 0, stream>>>(
                hb, qkvT + (size_t)l * 196608, bqkv + l * QKVW, qkvb,
                NTOK, QKVW, Dn, 0, nullptr, nullptr, Vt);
        } else {
            gemm_mfma<1><<<dim3(12, 64), 256, 0, stream>>>(
                hb, qkvT + (size_t)l * 196608, bqkv + l * QKVW, qkvb,
                NTOK, QKVW, Dn, 0, ln2g + (l - 1) * 256, ln2b + (l - 1) * 256, Vt);
        }
        if (fancy) {
            if (l < 3) {
                attn_fused<1><<<1024, 512, 0, stream>>>(
                    qkvb, Vt, bkT + l * Hn * Ln, bbT + l * Hn * Ln, ctxb, avg,
                    Pbuf + (size_t)l * PELEMS, 0);
            } else {
                attn_fused<2><<<1024, 512, 0, stream>>>(
                    qkvb, Vt, bkT + l * Hn * Ln, bbT + l * Hn * Ln, ctxb, avg,
                    Pbuf, 0);
            }
        } else {
            attn_fused<0><<<1024, 512, 0, stream>>>(
                qkvb, Vt, bkT + l * Hn * Ln, bbT + l * Hn * Ln, ctxb, avg,
                (ushort*)Pbuf, (l == 0) ? 1 : 0);
        }
        gemm_mfma<0><<<dim3(4, 64), 256, 0, stream>>>(
            ctxb, WoT + (size_t)l * 65536, bo + l * 256, t1,
            NTOK, Dn, Dn, 0, nullptr, nullptr, nullptr);
        // FF1 with fused ln1 + exact GELU
        gemm_mfma<1><<<dim3(16, 64), 256, 0, stream>>>(
            t1, W1T + (size_t)l * 262144, b1 + l * FFn, ffb,
            NTOK, FFn, Dn, 1, ln1g + l * 256, ln1b + l * 256, nullptr);
        gemm_mfma<0><<<dim3(4, 64), 256, 0, stream>>>(
            ffb, W2T + (size_t)l * 262144, b2 + l * 256, hb,
            NTOK, Dn, FFn, 0, nullptr, nullptr, nullptr);
    }
    // final ln2 (layer 3) before the mean
    layernorm_k<<<NTOK / 4, 256, 0, stream>>>(
        hb, ln2g + 3 * 256, ln2b + 3 * 256, hb);
    mean_part_k<<<64, 256, 0, stream>>>(hb, mpart);
    mean_final_k<<<Bn, 256, 0, stream>>>(mpart, out);
}

// Round 18
// 373.520 us; speedup vs baseline: 1.0974x; 1.0024x over previous
//
#include <hip/hip_runtime.h>
#include <hip/hip_bf16.h>
#include <math.h>

// Problem constants
#define Bn 4
#define Ln 1024
#define Vn 64
#define Dn 256
#define Hn 4
#define DKn 64
#define NLn 4
#define Mn 20
#define FFn 1024
#define NTOK (Bn * Ln)   // 4096
#define QKVW 768         // fused q|k|v width
#define LOG2E 1.4426950408889634f
#define PELEMS (Bn * Hn * Ln * Ln)   // 16777216 elements per layer P

typedef __attribute__((ext_vector_type(8))) short bf16x8;
typedef __attribute__((ext_vector_type(4))) float f32x4;

__device__ __forceinline__ ushort f2b(float f) {   // fp32 -> bf16 RNE
    uint u = __float_as_uint(f);
    u += 0x7fff + ((u >> 16) & 1);
    return (ushort)(u >> 16);
}
__device__ __forceinline__ float b2f(ushort u) {   // exact
    return __uint_as_float(((uint)u) << 16);
}

// ---------------------------------------------------------------------------
__global__ __launch_bounds__(256) void embed_k(const float* __restrict__ X,
                                               const float* __restrict__ E,
                                               ushort* __restrict__ Hb) {
    __shared__ float xs[Vn];
    int n = blockIdx.x, d = threadIdx.x;
    if (threadIdx.x < Vn) xs[threadIdx.x] = X[n * Vn + threadIdx.x];
    __syncthreads();
    float s = 0.f;
#pragma unroll
    for (int v = 0; v < Vn; ++v) s += xs[v] * E[v * Dn + d];
    Hb[(size_t)n * Dn + d] = f2b(s);
}

// ---------------------------------------------------------------------------
// bias tables, pre-scaled into exp2 domain
__global__ __launch_bounds__(256) void relbias_k(const float* __restrict__ rk,
                                                 const float* __restrict__ rb,
                                                 float* __restrict__ bkT,
                                                 float* __restrict__ bbT) {
    int tid = blockIdx.x * 256 + threadIdx.x;   // < NL*H*1024
    int dist = tid & 1023;
    int hh = (tid >> 10) & 3;
    int l = tid >> 12;
    float dd = (float)dist;
    if (dist > Mn) dd = (float)Mn + log2f((float)(dist - Mn));
    if (dd > 2.0f * Mn) dd = 2.0f * Mn;
    int idx = (int)dd;
    bkT[tid] = rk[(l * (2 * Mn + 1) + idx) * Hn + hh] * 0.125f * LOG2E;
    bbT[tid] = rb[(l * (2 * Mn + 1) + idx) * Hn + hh] * LOG2E;
}

// ---------------------------------------------------------------------------
__global__ __launch_bounds__(256) void prep_bias(const float* __restrict__ bq,
                                                 const float* __restrict__ bk,
                                                 const float* __restrict__ bv,
                                                 float* __restrict__ bqkv) {
    int idx = blockIdx.x * 256 + threadIdx.x;   // < NL*768
    int l = idx / QKVW, r = idx - l * QKVW;
    float v;
    if (r < 256)      v = bq[l * 256 + r];
    else if (r < 512) v = bk[l * 256 + r - 256];
    else              v = bv[l * 256 + r - 512];
    bqkv[idx] = v;
}

// ---------------------------------------------------------------------------
// Weight transpose + fp32->bf16: dst[c][r] = src[r][c]; grid.z = layer.
__global__ __launch_bounds__(256) void transpose_cvt(
    const float* __restrict__ src, ushort* __restrict__ dst,
    int R, int C, int srcLS, int dstLS) {
    __shared__ float s[32][33];
    src += (size_t)blockIdx.z * srcLS;
    dst += (size_t)blockIdx.z * dstLS;
    int r0 = blockIdx.y * 32, c0 = blockIdx.x * 32;
    int tx = threadIdx.x & 31, ty = threadIdx.x >> 5;
#pragma unroll
    for (int ii = 0; ii < 4; ++ii)
        s[ty + 8 * ii][tx] = src[(size_t)(r0 + ty + 8 * ii) * C + c0 + tx];
    __syncthreads();
#pragma unroll
    for (int ii = 0; ii < 4; ++ii)
        dst[(size_t)(c0 + ty + 8 * ii) * R + r0 + tx] = f2b(s[tx][ty + 8 * ii]);
}

// ---------------------------------------------------------------------------
// bf16 MFMA GEMM, BK=64.
#define GST 72
#define GEMM_KK_MFMA(KK)                                                      \
    {                                                                         \
        bf16x8 a0 = *(const bf16x8*)&As[(wm * 32 + l15) * GST + (KK)*32 + lg * 8];      \
        bf16x8 a1 = *(const bf16x8*)&As[(wm * 32 + 16 + l15) * GST + (KK)*32 + lg * 8]; \
        bf16x8 b0 = *(const bf16x8*)&Bs[(wn * 32 + l15) * GST + (KK)*32 + lg * 8];      \
        bf16x8 b1 = *(const bf16x8*)&Bs[(wn * 32 + 16 + l15) * GST + (KK)*32 + lg * 8]; \
        acc[0][0] = __builtin_amdgcn_mfma_f32_16x16x32_bf16(a0, b0, acc[0][0], 0, 0, 0); \
        acc[0][1] = __builtin_amdgcn_mfma_f32_16x16x32_bf16(a0, b1, acc[0][1], 0, 0, 0); \
        acc[1][0] = __builtin_amdgcn_mfma_f32_16x16x32_bf16(a1, b0, acc[1][0], 0, 0, 0); \
        acc[1][1] = __builtin_amdgcn_mfma_f32_16x16x32_bf16(a1, b1, acc[1][1], 0, 0, 0); \
    }

template <int LNA>
__global__ __launch_bounds__(256) void gemm_mfma(
    const ushort* __restrict__ A, const ushort* __restrict__ Bt,
    const float* __restrict__ bias, ushort* __restrict__ C,
    int M, int N, int K, int act,
    const float* __restrict__ lng, const float* __restrict__ lnb,
    ushort* __restrict__ Vt_out) {
    __shared__ __align__(16) ushort As[64 * GST];
    __shared__ __align__(16) ushort Bs[64 * GST];
    __shared__ float gl[256];
    __shared__ float bl[256];
    int t = threadIdx.x;
    int lane = t & 63, w = t >> 6;
    int wm = w >> 1, wn = w & 1;
    int l15 = lane & 15, lg = lane >> 4;
    int mBase = blockIdx.y * 64, nBase = blockIdx.x * 64;
    int lrow = t >> 2, lkc = (t & 3) * 16;
    const ushort* Ap = A + (size_t)(mBase + lrow) * K + lkc;
    const ushort* Bp = Bt + (size_t)(nBase + lrow) * K + lkc;
    f32x4 acc[2][2] = {};

    if constexpr (LNA) {
        uint4 areg[8];
        float s = 0.f;
#pragma unroll
        for (int kc = 0; kc < 4; ++kc)
#pragma unroll
            for (int h = 0; h < 2; ++h) {
                areg[kc * 2 + h] = *(const uint4*)(Ap + kc * 64 + h * 8);
                const ushort* e = (const ushort*)&areg[kc * 2 + h];
#pragma unroll
                for (int q = 0; q < 8; ++q) s += b2f(e[q]);
            }
        s += __shfl_xor(s, 1, 64);
        s += __shfl_xor(s, 2, 64);
        float mu = s * (1.0f / 256.0f);
        float vv = 0.f;
#pragma unroll
        for (int kc = 0; kc < 8; ++kc) {
            const ushort* e = (const ushort*)&areg[kc];
#pragma unroll
            for (int q = 0; q < 8; ++q) {
                float d = b2f(e[q]) - mu;
                vv += d * d;
            }
        }
        vv += __shfl_xor(vv, 1, 64);
        vv += __shfl_xor(vv, 2, 64);
        float rs = rsqrtf(vv * (1.0f / 256.0f) + 1e-5f);
        gl[t] = lng[t];
        bl[t] = lnb[t];
        __syncthreads();
#pragma unroll
        for (int kc = 0; kc < 4; ++kc) {
            uint4 bv0 = *(const uint4*)(Bp + kc * 64);
            uint4 bv1 = *(const uint4*)(Bp + kc * 64 + 8);
            __syncthreads();
#pragma unroll
            for (int h = 0; h < 2; ++h) {
                const ushort* e = (const ushort*)&areg[kc * 2 + h];
                ushort outv[8];
#pragma unroll
                for (int q = 0; q < 8; ++q) {
                    int col = kc * 64 + lkc + h * 8 + q;
                    outv[q] = f2b((b2f(e[q]) - mu) * rs * gl[col] + bl[col]);
                }
                *(uint4*)&As[lrow * GST + lkc + h * 8] = *(const uint4*)outv;
            }
            *(uint4*)&Bs[lrow * GST + lkc] = bv0;
            *(uint4*)&Bs[lrow * GST + lkc + 8] = bv1;
            __syncthreads();
            GEMM_KK_MFMA(0)
            GEMM_KK_MFMA(1)
        }
    } else {
        for (int k0 = 0; k0 < K; k0 += 64) {
            uint4 av0 = *(const uint4*)(Ap + k0);
            uint4 av1 = *(const uint4*)(Ap + k0 + 8);
            uint4 bv0 = *(const uint4*)(Bp + k0);
            uint4 bv1 = *(const uint4*)(Bp + k0 + 8);
            __syncthreads();
            *(uint4*)&As[lrow * GST + lkc] = av0;
            *(uint4*)&As[lrow * GST + lkc + 8] = av1;
            *(uint4*)&Bs[lrow * GST + lkc] = bv0;
            *(uint4*)&Bs[lrow * GST + lkc + 8] = bv1;
            __syncthreads();
            GEMM_KK_MFMA(0)
            GEMM_KK_MFMA(1)
        }
    }
    if (Vt_out != nullptr && nBase >= 512) {
#pragma unroll
        for (int ni = 0; ni < 2; ++ni) {
            int col = nBase + wn * 32 + ni * 16 + l15;
            float bc = bias[col];
            int d = col - 512;
#pragma unroll
            for (int mi = 0; mi < 2; ++mi) {
                int rb = mBase + wm * 32 + mi * 16 + lg * 4;
                int bb_ = rb >> 10, i_ = rb & 1023;
                size_t vb = ((size_t)(bb_ * 4 + (d >> 6)) * 64 + (d & 63)) * Ln + i_;
                ushort o4[4];
#pragma unroll
                for (int j = 0; j < 4; ++j) o4[j] = f2b(acc[mi][ni][j] + bc);
                *(ushort4*)&Vt_out[vb] = *(const ushort4*)o4;
            }
        }
        return;
    }
#pragma unroll
    for (int ni = 0; ni < 2; ++ni) {
        int col = nBase + wn * 32 + ni * 16 + l15;
        float bc = bias[col];
#pragma unroll
        for (int mi = 0; mi < 2; ++mi) {
            int rb = mBase + wm * 32 + mi * 16 + lg * 4;
#pragma unroll
            for (int j = 0; j < 4; ++j) {
                float v = acc[mi][ni][j] + bc;
                if (act) v = v * 0.5f * (1.0f + erff(v * 0.7071067811865475f));
                C[(size_t)(rb + j) * N + col] = f2b(v);
            }
        }
    }
}

// ---------------------------------------------------------------------------
// MFMA flash attention, 8 waves. launch_bounds(512,4): VGPR cap 128 so the
// compiler + explicit prefetch keep next-chunk K/V loads in flight (ILP),
// trading occupancy (4->2 blocks/CU min) for memory pipelining.
#define PWST 40
#define NW 8
template <int MODE>
__global__ __launch_bounds__(512, 4) void attn_fused(
    const ushort* __restrict__ qkv, const ushort* __restrict__ Vt,
    const float* __restrict__ bkTab, const float* __restrict__ bbTab,
    ushort* __restrict__ ctx, float* __restrict__ avg,
    ushort* __restrict__ Pout, int first) {
    __shared__ float bk_l[Ln];
    __shared__ float bb_l[Ln];
    __shared__ __align__(16) char uni[20480];   // Pw: 8x2560 | Opart: 4x4096
    __shared__ float mm[NW][16];
    __shared__ float ll[NW][16];

    int t = threadIdx.x;
    int lane = t & 63, w = t >> 6;        // w in [0,8)
    int wn = w & 3, wc = w >> 2;          // col slice, chunk half
    int l15 = lane & 15, lg = lane >> 4;

    ushort* pwh = (ushort*)&uni[w * 2560];          // [16*PWST] P hi
    ushort* pwl = (ushort*)&uni[w * 2560 + 1280];   // [16*PWST] P lo

    int bid = blockIdx.x;
    int xcd = bid & 7, sub = bid >> 3;    // sub in [0,128)
    int bh = xcd * 2 + (sub >> 6);
    int q = sub & 63;
    int b = bh >> 2, hh = bh & 3;
    int i0 = q * 16;

#pragma unroll
    for (int ii = 0; ii < 2; ++ii) {
        bk_l[t + 512 * ii] = bkTab[hh * Ln + t + 512 * ii];
        bb_l[t + 512 * ii] = bbTab[hh * Ln + t + 512 * ii];
    }
    __syncthreads();

    // Q fragment (A-operand): row = i0 + l15, k = lg*8 (+32)
    bf16x8 qa0, qa1;
    {
        const ushort* qp = qkv + (size_t)(b * Ln + i0 + l15) * QKVW + hh * DKn;
        qa0 = *(const bf16x8*)(qp + lg * 8);
        qa1 = *(const bf16x8*)(qp + 32 + lg * 8);
    }

    const ushort* kbase = qkv + (size_t)(b * Ln) * QKVW + Dn + hh * DKn;

    // ---- QK pass over this wave's 8 chunks, K prefetched 1 chunk ahead ------
    f32x4 sv[8];
    float m[4] = {-1e30f, -1e30f, -1e30f, -1e30f};
    bf16x8 k0n, k1n;
    {
        const ushort* kp = kbase + (size_t)(wc * 8 * 64 + wn * 16 + l15) * QKVW;
        k0n = *(const bf16x8*)(kp + lg * 8);
        k1n = *(const bf16x8*)(kp + 32 + lg * 8);
    }
#pragma unroll
    for (int cl = 0; cl < 8; ++cl) {
        int c = wc * 8 + cl;
        bf16x8 k0 = k0n, k1 = k1n;
        if (cl < 7) {
            const ushort* kp = kbase + (size_t)((c + 1) * 64 + wn * 16 + l15) * QKVW;
            k0n = *(const bf16x8*)(kp + lg * 8);
            k1n = *(const bf16x8*)(kp + 32 + lg * 8);
        }
        f32x4 acc = {};
        acc = __builtin_amdgcn_mfma_f32_16x16x32_bf16(qa0, k0, acc, 0, 0, 0);
        acc = __builtin_amdgcn_mfma_f32_16x16x32_bf16(qa1, k1, acc, 0, 0, 0);
        int j = c * 64 + wn * 16 + l15;
#pragma unroll
        for (int r = 0; r < 4; ++r) {
            int i = i0 + lg * 4 + r;
            int dist = (i > j) ? (i - j) : (j - i);
            float s = acc[r] * bk_l[dist] + bb_l[dist];
            sv[cl][r] = s;
            m[r] = fmaxf(m[r], s);
        }
    }
    // merge max over the 16 l15-lanes
#pragma unroll
    for (int mask = 1; mask < 16; mask <<= 1)
#pragma unroll
        for (int r = 0; r < 4; ++r) m[r] = fmaxf(m[r], __shfl_xor(m[r], mask, 64));
    // merge max across the 8 waves
    if (l15 == 0)
#pragma unroll
        for (int r = 0; r < 4; ++r) mm[w][lg * 4 + r] = m[r];
    __syncthreads();
#pragma unroll
    for (int r = 0; r < 4; ++r) {
        int row = lg * 4 + r;
        float m0 = fmaxf(fmaxf(mm[0][row], mm[1][row]), fmaxf(mm[2][row], mm[3][row]));
        float m1 = fmaxf(fmaxf(mm[4][row], mm[5][row]), fmaxf(mm[6][row], mm[7][row]));
        m[r] = fmaxf(m0, m1);
    }
    // p_unnorm = exp2(s - m); row sums
    float lsum[4] = {0.f, 0.f, 0.f, 0.f};
#pragma unroll
    for (int cl = 0; cl < 8; ++cl)
#pragma unroll
        for (int r = 0; r < 4; ++r) {
            float p = exp2f(sv[cl][r] - m[r]);
            sv[cl][r] = p;
            lsum[r] += p;
        }
#pragma unroll
    for (int mask = 1; mask < 16; mask <<= 1)
#pragma unroll
        for (int r = 0; r < 4; ++r) lsum[r] += __shfl_xor(lsum[r], mask, 64);
    if (l15 == 0)
#pragma unroll
        for (int r = 0; r < 4; ++r) ll[w][lg * 4 + r] = lsum[r];
    __syncthreads();
    float invl[4];
#pragma unroll
    for (int r = 0; r < 4; ++r) {
        int row = lg * 4 + r;
        invl[r] = 1.0f / (ll[0][row] + ll[1][row] + ll[2][row] + ll[3][row] +
                          ll[4][row] + ll[5][row] + ll[6][row] + ll[7][row]);
    }

    // ---- PV partial-O + P/avg output, V prefetched 1 iter ahead -------------
    const ushort* vbase = Vt + (size_t)bh * DKn * Ln;       // [64 d][Ln k]
    float* avgrow = avg + ((size_t)bh * Ln + i0) * Ln;      // MODE 0
    int iw = lane >> 2, jq = lane & 3;                      // P tile map
    f32x4 acco[4] = {};
    bf16x8 va0n, va1n, va2n, va3n;
    {
        int c0 = wc * 8, c1 = c0 + 1;
        int kcol = (lg < 2 ? c0 : c1) * 64 + wn * 16 + (lg & 1) * 8;
        va0n = *(const bf16x8*)(vbase + (size_t)(0 * 16 + l15) * Ln + kcol);
        va1n = *(const bf16x8*)(vbase + (size_t)(1 * 16 + l15) * Ln + kcol);
        va2n = *(const bf16x8*)(vbase + (size_t)(2 * 16 + l15) * Ln + kcol);
        va3n = *(const bf16x8*)(vbase + (size_t)(3 * 16 + l15) * Ln + kcol);
    }
#pragma unroll
    for (int p = 0; p < 4; ++p) {
        const int c0 = wc * 8 + 2 * p, c1 = c0 + 1;
        bf16x8 va0 = va0n, va1 = va1n, va2 = va2n, va3 = va3n;
        if (p < 3) {
            int kcol = (lg < 2 ? (c0 + 2) : (c1 + 2)) * 64 + wn * 16 + (lg & 1) * 8;
            va0n = *(const bf16x8*)(vbase + (size_t)(0 * 16 + l15) * Ln + kcol);
            va1n = *(const bf16x8*)(vbase + (size_t)(1 * 16 + l15) * Ln + kcol);
            va2n = *(const bf16x8*)(vbase + (size_t)(2 * 16 + l15) * Ln + kcol);
            va3n = *(const bf16x8*)(vbase + (size_t)(3 * 16 + l15) * Ln + kcol);
        }
        float aold[2][4];
        if (MODE == 0 && !first) {
#pragma unroll
            for (int cc = 0; cc < 2; ++cc)
#pragma unroll
                for (int r = 0; r < 4; ++r)
                    aold[cc][r] = avgrow[(size_t)(lg * 4 + r) * Ln +
                                         (c0 + cc) * 64 + wn * 16 + l15];
        }
        // stage P (hi/lo) into wave-private LDS
#pragma unroll
        for (int cc = 0; cc < 2; ++cc)
#pragma unroll
            for (int r = 0; r < 4; ++r) {
                float pv = sv[2 * p + cc][r] * invl[r];
                sv[2 * p + cc][r] = pv;
                ushort ph = f2b(pv);
                int off = (lg * 4 + r) * PWST + cc * 16 + l15;
                pwh[off] = ph;
                pwl[off] = f2b(pv - b2f(ph));
            }
        // B fragments from own LDS (same-wave RAW: compiler lgkmcnt)
        bf16x8 pbh = *(const bf16x8*)&pwh[l15 * PWST + lg * 8];
        bf16x8 pbl = *(const bf16x8*)&pwl[l15 * PWST + lg * 8];
        acco[0] = __builtin_amdgcn_mfma_f32_16x16x32_bf16(va0, pbh, acco[0], 0, 0, 0);
        acco[1] = __builtin_amdgcn_mfma_f32_16x16x32_bf16(va1, pbh, acco[1], 0, 0, 0);
        acco[2] = __builtin_amdgcn_mfma_f32_16x16x32_bf16(va2, pbh, acco[2], 0, 0, 0);
        acco[3] = __builtin_amdgcn_mfma_f32_16x16x32_bf16(va3, pbh, acco[3], 0, 0, 0);
        acco[0] = __builtin_amdgcn_mfma_f32_16x16x32_bf16(va0, pbl, acco[0], 0, 0, 0);
        acco[1] = __builtin_amdgcn_mfma_f32_16x16x32_bf16(va1, pbl, acco[1], 0, 0, 0);
        acco[2] = __builtin_amdgcn_mfma_f32_16x16x32_bf16(va2, pbl, acco[2], 0, 0, 0);
        acco[3] = __builtin_amdgcn_mfma_f32_16x16x32_bf16(va3, pbl, acco[3], 0, 0, 0);
        if (MODE == 0) {
#pragma unroll
            for (int cc = 0; cc < 2; ++cc)
#pragma unroll
                for (int r = 0; r < 4; ++r) {
                    float v = 0.25f * sv[2 * p + cc][r];
                    if (!first) v += aold[cc][r];
                    avgrow[(size_t)(lg * 4 + r) * Ln + (c0 + cc) * 64 + wn * 16 + l15] = v;
                }
        } else if (MODE == 1) {
            // tile-linear P store: 512B contiguous per wave per cc
            size_t tb = ((((size_t)bid * 8 + w) * 4 + p) * 2) * 256 + (size_t)lane * 4;
            ushort4 ph0 = *(const ushort4*)&pwh[iw * PWST + 0 * 16 + jq * 4];
            ushort4 ph1 = *(const ushort4*)&pwh[iw * PWST + 1 * 16 + jq * 4];
            *(ushort4*)&Pout[tb] = ph0;
            *(ushort4*)&Pout[tb + 256] = ph1;
        } else {
            // MODE 2: read P0..P2 tile-linear, add own P, write avg f32
#pragma unroll
            for (int cc = 0; cc < 2; ++cc) {
                int c = c0 + cc;
                size_t tb = ((((size_t)bid * 8 + w) * 4 + p) * 2 + cc) * 256 +
                            (size_t)lane * 4;
                ushort4 p0 = *(const ushort4*)&Pout[tb];
                ushort4 p1 = *(const ushort4*)&Pout[(size_t)PELEMS + tb];
                ushort4 p2 = *(const ushort4*)&Pout[(size_t)2 * PELEMS + tb];
                ushort4 p3 = *(const ushort4*)&pwh[iw * PWST + cc * 16 + jq * 4];
                const ushort* q0 = (const ushort*)&p0;
                const ushort* q1 = (const ushort*)&p1;
                const ushort* q2 = (const ushort*)&p2;
                const ushort* q3 = (const ushort*)&p3;
                size_t base = ((size_t)(bh * Ln) + i0 + iw) * Ln +
                              c * 64 + wn * 16 + jq * 4;
                float4 o;
                float* op_ = (float*)&o;
#pragma unroll
                for (int k = 0; k < 4; ++k)
                    op_[k] = 0.25f * (b2f(q0[k]) + b2f(q1[k]) + b2f(q2[k]) + b2f(q3[k]));
                *(float4*)&avg[base] = o;
            }
        }
    }

    // ---- reduce partial O across 8 waves (Opart aliases Pw) ------------------
    __syncthreads();   // all PV done; Pw region dead
    {
        float* op = (float*)&uni[wn * 4096];
        if (wc == 1) {
#pragma unroll
            for (int dg = 0; dg < 4; ++dg)
#pragma unroll
                for (int r = 0; r < 4; ++r)
                    op[(dg * 16 + lg * 4 + r) * 16 + l15] = acco[dg][r];
        }
    }
    __syncthreads();
    {
        float* op = (float*)&uni[wn * 4096];
        if (wc == 0) {
#pragma unroll
            for (int dg = 0; dg < 4; ++dg)
#pragma unroll
                for (int r = 0; r < 4; ++r)
                    op[(dg * 16 + lg * 4 + r) * 16 + l15] += acco[dg][r];
        }
    }
    __syncthreads();
#pragma unroll
    for (int k = 0; k < 2; ++k) {
        int idx = t + 512 * k;          // idx = d*16 + i
        float v = ((const float*)&uni[0])[idx] + ((const float*)&uni[4096])[idx] +
                  ((const float*)&uni[8192])[idx] + ((const float*)&uni[12288])[idx];
        int dd = idx >> 4, ii = idx & 15;
        ctx[(size_t)(b * Ln + i0 + ii) * Dn + hh * DKn + dd] = f2b(v);
    }
}

// ---------------------------------------------------------------------------
__global__ __launch_bounds__(256) void layernorm_k(const ushort* __restrict__ X,
                                                   const float* __restrict__ g,
                                                   const float* __restrict__ bta,
                                                   ushort* __restrict__ Y) {
    int w = threadIdx.x >> 6, lane = threadIdx.x & 63;
    int row = blockIdx.x * 4 + w;
    const ushort* xr = X + (size_t)row * Dn;
    float x[4];
#pragma unroll
    for (int ii = 0; ii < 4; ++ii) x[ii] = b2f(xr[lane + 64 * ii]);
    float s = x[0] + x[1] + x[2] + x[3];
#pragma unroll
    for (int m = 1; m < 64; m <<= 1) s += __shfl_xor(s, m, 64);
    float mu = s * (1.0f / 256.0f);
    float vs = 0.f;
#pragma unroll
    for (int ii = 0; ii < 4; ++ii) {
        float d = x[ii] - mu;
        vs += d * d;
    }
#pragma unroll
    for (int m = 1; m < 64; m <<= 1) vs += __shfl_xor(vs, m, 64);
    float rs = rsqrtf(vs * (1.0f / 256.0f) + 1e-5f);
#pragma unroll
    for (int ii = 0; ii < 4; ++ii) {
        int d = lane + 64 * ii;
        Y[(size_t)row * Dn + d] = f2b((x[ii] - mu) * rs * g[d] + bta[d]);
    }
}

// ---------------------------------------------------------------------------
__global__ __launch_bounds__(256) void mean_part_k(const ushort* __restrict__ Hb,
                                                   float* __restrict__ part) {
    int blk = blockIdx.x;            // 64 = 4 b x 16 groups
    int b = blk >> 4, g = blk & 15;
    int d = threadIdx.x;
    float s = 0.f;
#pragma unroll
    for (int r = 0; r < 64; ++r)
        s += b2f(Hb[(size_t)(b * Ln + g * 64 + r) * Dn + d]);
    part[(size_t)blk * Dn + d] = s;
}
__global__ __launch_bounds__(256) void mean_final_k(const float* __restrict__ part,
                                                    float* __restrict__ out) {
    int b = blockIdx.x, d = threadIdx.x;
    float s = 0.f;
#pragma unroll
    for (int g = 0; g < 16; ++g) s += part[(size_t)(b * 16 + g) * Dn + d];
    out[b * Dn + d] = s * (1.0f / (float)Ln);
}

// ---------------------------------------------------------------------------
extern "C" void kernel_launch(void* const* d_in, const int* in_sizes, int n_in,
                              void* d_out, int out_size, void* d_ws, size_t ws_size,
                              hipStream_t stream) {
    const float* x    = (const float*)d_in[0];
    const float* emb  = (const float*)d_in[1];
    const float* Wq   = (const float*)d_in[2];
    const float* bq   = (const float*)d_in[3];
    const float* Wk   = (const float*)d_in[4];
    const float* bk   = (const float*)d_in[5];
    const float* Wv   = (const float*)d_in[6];
    const float* bv   = (const float*)d_in[7];
    const float* Wo   = (const float*)d_in[8];
    const float* bo   = (const float*)d_in[9];
    const float* rk   = (const float*)d_in[10];
    const float* rb   = (const float*)d_in[11];
    const float* ln1g = (const float*)d_in[12];
    const float* ln1b = (const float*)d_in[13];
    const float* W1   = (const float*)d_in[14];
    const float* b1   = (const float*)d_in[15];
    const float* W2   = (const float*)d_in[16];
    const float* b2   = (const float*)d_in[17];
    const float* ln2g = (const float*)d_in[18];
    const float* ln2b = (const float*)d_in[19];

    float* out = (float*)d_out;
    float* avg = out + Bn * Dn;

    char* ws = (char*)d_ws;
    const size_t MB = 1024 * 1024;
    ushort* hb   = (ushort*)(ws);             // 2 MB
    ushort* qkvb = (ushort*)(ws + 2 * MB);    // 6 MB
    ushort* ctxb = (ushort*)(ws + 8 * MB);    // 2 MB
    ushort* t1   = (ushort*)(ws + 10 * MB);   // 2 MB
    ushort* ffb  = (ushort*)(ws + 12 * MB);   // 8 MB
    ushort* qkvT = (ushort*)(ws + 20 * MB);   // 1.5 MB
    ushort* WoT  = (ushort*)(ws + 22 * MB);   // 0.5 MB
    ushort* W1T  = (ushort*)(ws + 23 * MB);   // 2 MB
    ushort* W2T  = (ushort*)(ws + 25 * MB);   // 2 MB
    float*  bqkv = (float*)(ws + 27 * MB);
    float*  bkT  = (float*)(ws + 27 * MB + 65536);
    float*  bbT  = (float*)(ws + 27 * MB + 131072);
    ushort* Vt   = (ushort*)(ws + 30 * MB);   // 2 MB
    float*  mpart= (float*)(ws + 33 * MB);    // 64 KB
    ushort* Pbuf = (ushort*)(ws + 36 * MB);   // 3 x 32 MB used (mode 1/2)

    const size_t need = 36 * MB + (size_t)3 * PELEMS * sizeof(ushort);
    const bool fancy = (ws_size >= need);

    embed_k<<<NTOK, 256, 0, stream>>>(x, emb, hb);
    relbias_k<<<64, 256, 0, stream>>>(rk, rb, bkT, bbT);
    prep_bias<<<12, 256, 0, stream>>>(bq, bk, bv, bqkv);

    dim3 t88(8, 8, NLn);
    transpose_cvt<<<t88, 256, 0, stream>>>(Wq, qkvT + 0,      256, 256, 65536, 196608);
    transpose_cvt<<<t88, 256, 0, stream>>>(Wk, qkvT + 65536,  256, 256, 65536, 196608);
    transpose_cvt<<<t88, 256, 0, stream>>>(Wv, qkvT + 131072, 256, 256, 65536, 196608);
    transpose_cvt<<<t88, 256, 0, stream>>>(Wo, WoT,           256, 256, 65536, 65536);
    transpose_cvt<<<dim3(32, 8, NLn), 256, 0, stream>>>(W1, W1T, 256, 1024, 262144, 262144);
    transpose_cvt<<<dim3(8, 32, NLn), 256, 0, stream>>>(W2, W2T, 1024, 256, 262144, 262144);

    for (int l = 0; l < NLn; ++l) {
        // QKV projection (V written transposed into Vt via epilogue);
        // layers 1..3 fuse previous layer's ln2 into A.
        if (l == 0) {
            gemm_mfma<0><<<dim3(12, 64), 256, 0, stream>>>(
                hb, qkvT + (size_t)l * 196608, bqkv + l * QKVW, qkvb,
                NTOK, QKVW, Dn, 0, nullptr, nullptr, Vt);
        } else {
            gemm_mfma<1><<<dim3(12, 64), 256, 0, stream>>>(
                hb, qkvT + (size_t)l * 196608, bqkv + l * QKVW, qkvb,
                NTOK, QKVW, Dn, 0, ln2g + (l - 1) * 256, ln2b + (l - 1) * 256, Vt);
        }
        if (fancy) {
            if (l < 3) {
                attn_fused<1><<<1024, 512, 0, stream>>>(
                    qkvb, Vt, bkT + l * Hn * Ln, bbT + l * Hn * Ln, ctxb, avg,
                    Pbuf + (size_t)l * PELEMS, 0);
            } else {
                attn_fused<2><<<1024, 512, 0, stream>>>(
                    qkvb, Vt, bkT + l * Hn * Ln, bbT + l * Hn * Ln, ctxb, avg,
                    Pbuf, 0);
            }
        } else {
            attn_fused<0><<<1024, 512, 0, stream>>>(
                qkvb, Vt, bkT + l * Hn * Ln, bbT + l * Hn * Ln, ctxb, avg,
                (ushort*)Pbuf, (l == 0) ? 1 : 0);
        }
        gemm_mfma<0><<<dim3(4, 64), 256, 0, stream>>>(
            ctxb, WoT + (size_t)l * 65536, bo + l * 256, t1,
            NTOK, Dn, Dn, 0, nullptr, nullptr, nullptr);
        // FF1 with fused ln1 + exact GELU
        gemm_mfma<1><<<dim3(16, 64), 256, 0, stream>>>(
            t1, W1T + (size_t)l * 262144, b1 + l * FFn, ffb,
            NTOK, FFn, Dn, 1, ln1g + l * 256, ln1b + l * 256, nullptr);
        gemm_mfma<0><<<dim3(4, 64), 256, 0, stream>>>(
            ffb, W2T + (size_t)l * 262144, b2 + l * 256, hb,
            NTOK, Dn, FFn, 0, nullptr, nullptr, nullptr);
    }
    // final ln2 (layer 3) before the mean
    layernorm_k<<<NTOK / 4, 256, 0, stream>>>(
        hb, ln2g + 3 * 256, ln2b + 3 * 256, hb);
    mean_part_k<<<64, 256, 0, stream>>>(hb, mpart);
    mean_final_k<<<Bn, 256, 0, stream>>>(mpart, out);
}